// Round 1
// 15310.925 us; speedup vs baseline: 1.1782x; 1.1782x over previous
//
#include <hip/hip_runtime.h>
#include <hip/hip_bf16.h>
#include <hip/hip_cooperative_groups.h>
#include <math.h>

namespace cg = cooperative_groups;

#define B_    256
#define S_    128
#define EMB_  512
#define H2_   512
#define HID_  1024
#define CTX_  64
#define VOC_  32000
#define TMAX_ 40
#define SOS_  2

typedef unsigned short u16;
typedef __attribute__((ext_vector_type(8))) short short8;
typedef __attribute__((ext_vector_type(4))) float f32x4;

__device__ __forceinline__ float4 ld4(const float* p) {
    return *reinterpret_cast<const float4*>(p);
}
__device__ __forceinline__ float sigmoidf_(float x) { return 1.f / (1.f + expf(-x)); }
__device__ __forceinline__ u16 f2bf(float x) {
    union { float f; unsigned int u; } v; v.f = x;
    unsigned int r = v.u + 0x7FFFu + ((v.u >> 16) & 1u);
    return (u16)(r >> 16);
}
__device__ __forceinline__ unsigned pk2(float a, float b) {
    float2 t; t.x = a; t.y = b;
    __hip_bfloat162 h = __float22bfloat162_rn(t);
    return *reinterpret_cast<unsigned*>(&h);
}
// merge two (value desc, index asc)-ordered top-2 pairs
__device__ __forceinline__ void merge_top2(float& v1, int& i1, float& v2, int& i2,
                                           float ov1, int oi1, float ov2, int oi2)
{
    if (ov1 > v1 || (ov1 == v1 && oi1 < i1)) {
        float tv = v1; int ti = i1;
        v1 = ov1; i1 = oi1;
        if (ov2 > tv || (ov2 == tv && oi2 < ti)) { v2 = ov2; i2 = oi2; }
        else                                     { v2 = tv;  i2 = ti;  }
    } else {
        if (ov1 > v2 || (ov1 == v2 && oi1 < i2)) { v2 = ov1; i2 = oi1; }
    }
}

// ---------------------------------------------------------------------------
// fp32 tiled GEMM (kept for the one-shot gctx GEMM):
// C[m][n] = sum_k A[m][k]*B[n][k] (+bias) (+addsrc)
// AMODE: 0 plain A (lda) | 2 decoder-ctx composite | 3 emb gather via ids[m]
// BIASM: 0 -> bias[n], 1 -> bias[m]
// ---------------------------------------------------------------------------
template<int BM, int BN, int TM, int TN, int AMODE, int BGATHER, int BIASM>
__launch_bounds__(256)
__global__ void gemm_nt(const float* __restrict__ Ap,
                        const int*   __restrict__ ids,
                        const float* __restrict__ Ex,
                        const float* __restrict__ Bp, int ldb, int bofs,
                        const float* __restrict__ bias,
                        const float* __restrict__ addsrc,
                        float* __restrict__ Cp, int ldc,
                        int lda, int K, int s_base, int sdir)
{
    constexpr int BK = 32;
    __shared__ float As[BK][BM + 4];
    __shared__ float Bs[BK][BN + 4];
    const int t  = threadIdx.x;
    const int tx = t & 15, ty = t >> 4;
    const int m_base = blockIdx.y * BM;
    const int n_base = blockIdx.x * BN;

    float acc[TM][TN];
#pragma unroll
    for (int i = 0; i < TM; ++i)
#pragma unroll
        for (int j = 0; j < TN; ++j) acc[i][j] = 0.f;

    constexpr int A_PER = BM * BK / 4 / 256;
    constexpr int B_PER = BN * BK / 4 / 256;

    for (int k0 = 0; k0 < K; k0 += BK) {
#pragma unroll
        for (int j = 0; j < A_PER; ++j) {
            int f   = t + j * 256;
            int row = f >> 3;
            int kk  = (f & 7) << 2;
            int m   = m_base + row;
            float4 v;
            if constexpr (AMODE == 0) {
                v = ld4(Ap + (size_t)m * lda + k0 + kk);
            } else if constexpr (AMODE == 3) {
                int id = ids[m];
                v = ld4(Ex + (size_t)id * EMB_ + k0 + kk);
            } else {  // AMODE == 2
                int k = k0 + kk;
                if (k < HID_) v = ld4(Ap + (size_t)m * HID_ + k);
                else          v = ld4(Ex + (size_t)m * CTX_ + (k - HID_));
            }
            As[kk + 0][row] = v.x; As[kk + 1][row] = v.y;
            As[kk + 2][row] = v.z; As[kk + 3][row] = v.w;
        }
#pragma unroll
        for (int j = 0; j < B_PER; ++j) {
            int f   = t + j * 256;
            int row = f >> 3;
            int kk  = (f & 7) << 2;
            float4 v;
            if constexpr (BGATHER == 1) {
                int n = n_base + row;
                int s = n >> 8, b = n & 255;
                int id = ids[b * S_ + s_base + sdir * s];
                v = ld4(Ex + (size_t)id * EMB_ + k0 + kk);
            } else {
                v = ld4(Bp + (size_t)(n_base + row) * ldb + bofs + k0 + kk);
            }
            Bs[kk + 0][row] = v.x; Bs[kk + 1][row] = v.y;
            Bs[kk + 2][row] = v.z; Bs[kk + 3][row] = v.w;
        }
        __syncthreads();
#pragma unroll
        for (int kk = 0; kk < BK; ++kk) {
            float a[TM], b[TN];
            *(float4*)&a[0] = ld4(&As[kk][ty * TM]);
            if constexpr (TM == 8) *(float4*)&a[4] = ld4(&As[kk][ty * TM + 4]);
            *(float4*)&b[0] = ld4(&Bs[kk][tx * TN]);
            if constexpr (TN == 8) *(float4*)&b[4] = ld4(&Bs[kk][tx * TN + 4]);
#pragma unroll
            for (int i = 0; i < TM; ++i)
#pragma unroll
                for (int j = 0; j < TN; ++j) acc[i][j] += a[i] * b[j];
        }
        __syncthreads();
    }
#pragma unroll
    for (int i = 0; i < TM; ++i) {
        int m = m_base + ty * TM + i;
#pragma unroll
        for (int j = 0; j < TN; ++j) {
            int n = n_base + tx * TN + j;
            float v = acc[i][j];
            if (bias) v += BIASM ? bias[m] : bias[n];
            if (addsrc) v += addsrc[(size_t)m * ldc + n];
            Cp[(size_t)m * ldc + n] = v;
        }
    }
}

// ---------------------------------------------------------------------------
// Encoder gx GEMM, BOTH directions in one launch (blockIdx.z = dir).
// gxT[col][s][b] = wih @ emb[ids]^T + bih[col] ; 16 steps per chunk.
// M=1536, N=4096 (16 steps x 256 batch), K=512.  grid (32, 12, 2).
// ---------------------------------------------------------------------------
__launch_bounds__(256)
__global__ void enc_gx(const float* __restrict__ wih_f, const float* __restrict__ wih_b,
                       const float* __restrict__ bih_f, const float* __restrict__ bih_b,
                       const int* __restrict__ ids, const float* __restrict__ emb,
                       float* __restrict__ gxT_f, float* __restrict__ gxT_b, int c)
{
    constexpr int BK = 32;
    __shared__ float As[BK][132];
    __shared__ float Bs[BK][132];
    const int t  = threadIdx.x;
    const int tx = t & 15, ty = t >> 4;
    const int dz = blockIdx.z;
    const float* Ap   = dz ? wih_b : wih_f;
    const float* bias = dz ? bih_b : bih_f;
    float*       Cp   = dz ? gxT_b : gxT_f;
    const int s_base  = dz ? (127 - 16 * c) : (16 * c);
    const int sdir    = dz ? -1 : 1;
    const int m_base = blockIdx.y * 128;
    const int n_base = blockIdx.x * 128;

    float acc[8][8];
#pragma unroll
    for (int i = 0; i < 8; ++i)
#pragma unroll
        for (int j = 0; j < 8; ++j) acc[i][j] = 0.f;

    for (int k0 = 0; k0 < 512; k0 += BK) {
#pragma unroll
        for (int j = 0; j < 4; ++j) {
            int f   = t + j * 256;
            int row = f >> 3;
            int kk  = (f & 7) << 2;
            float4 v = ld4(Ap + (size_t)(m_base + row) * 512 + k0 + kk);
            As[kk + 0][row] = v.x; As[kk + 1][row] = v.y;
            As[kk + 2][row] = v.z; As[kk + 3][row] = v.w;
        }
#pragma unroll
        for (int j = 0; j < 4; ++j) {
            int f   = t + j * 256;
            int row = f >> 3;
            int kk  = (f & 7) << 2;
            int n = n_base + row;
            int s = n >> 8, b = n & 255;
            int id = ids[b * S_ + s_base + sdir * s];
            float4 v = ld4(emb + (size_t)id * EMB_ + k0 + kk);
            Bs[kk + 0][row] = v.x; Bs[kk + 1][row] = v.y;
            Bs[kk + 2][row] = v.z; Bs[kk + 3][row] = v.w;
        }
        __syncthreads();
#pragma unroll
        for (int kk = 0; kk < BK; ++kk) {
            float a[8], b[8];
            *(float4*)&a[0] = ld4(&As[kk][ty * 8]);
            *(float4*)&a[4] = ld4(&As[kk][ty * 8 + 4]);
            *(float4*)&b[0] = ld4(&Bs[kk][tx * 8]);
            *(float4*)&b[4] = ld4(&Bs[kk][tx * 8 + 4]);
#pragma unroll
            for (int i = 0; i < 8; ++i)
#pragma unroll
                for (int j = 0; j < 8; ++j) acc[i][j] += a[i] * b[j];
        }
        __syncthreads();
    }
#pragma unroll
    for (int i = 0; i < 8; ++i) {
        int m = m_base + ty * 8 + i;
        float bm = bias[m];
#pragma unroll
        for (int j = 0; j < 8; ++j) {
            int n = n_base + tx * 8 + j;
            Cp[(size_t)m * 4096 + n] = acc[i][j] + bm;
        }
    }
}

// ---------------------------------------------------------------------------
// Cooperative encoder recurrence: 256 blocks x 512 thr, 16 steps per launch.
// Block (dir, ub, rb) owns units [8ub,8ub+8) x rows [128rb,128rb+128).
// whh slice (48KB) LDS-resident; h ping-pongs via hT; grid.sync() per step.
// gxT layout: [col 1536][step 16][batch 256]  (stride 4096 per col)
// ---------------------------------------------------------------------------
__launch_bounds__(512)
__global__ void enc_coop(const float* __restrict__ gxT_f, const float* __restrict__ gxT_b,
                         const float* __restrict__ whh_f, const float* __restrict__ whh_b,
                         const float* __restrict__ bhh_f, const float* __restrict__ bhh_b,
                         float* __restrict__ hT, int nsteps)
{
    cg::grid_group grid = cg::this_grid();
    __shared__ float wlds[8 * 3 * 512];     // 48 KB
    __shared__ float hs[2][128][9];
    const int bid = blockIdx.x;
    const int dir = bid >> 7, blk = bid & 127;
    const int ub = blk >> 1, rb = blk & 1;
    const float* whh = dir ? whh_b : whh_f;
    const float* bhh = dir ? bhh_b : bhh_f;
    const float* gxT = dir ? gxT_b : gxT_f;
    float* hbase = hT + (size_t)dir * (2 * 512 * 256);
    const int t = threadIdx.x;

    for (int i = t * 4; i < 8 * 3 * 512; i += 512 * 4) {
        int ug = i >> 9, k = i & 511;
        int u = ug / 3, g = ug % 3;
        *(float4*)&wlds[i] = ld4(whh + ((size_t)(g * 512 + ub * 8 + u)) * 512 + k);
    }
    const int rl = t & 127;
    const int usub = t >> 7;
    const int r0 = rb * 128;
    const int r = r0 + rl;
    float bh[2][3];
#pragma unroll
    for (int uu = 0; uu < 2; ++uu)
#pragma unroll
        for (int g = 0; g < 3; ++g) bh[uu][g] = bhh[g * 512 + ub * 8 + usub * 2 + uu];
    const int skk = t >> 6;
    const int srr = (t & 63) * 2;
    __syncthreads();

    for (int st = 0; st < nsteps; ++st) {
        const float* hin  = hbase + (st & 1) * (512 * 256);
        float*       hout = hbase + ((st & 1) ^ 1) * (512 * 256);
        {
            float2 v = *(const float2*)(hin + (size_t)skk * 256 + r0 + srr);
            hs[0][srr][skk] = v.x; hs[0][srr + 1][skk] = v.y;
        }
        __syncthreads();
        float acc[2][3] = {{0.f,0.f,0.f},{0.f,0.f,0.f}};
        for (int kt = 0; kt < 64; ++kt) {
            int cur = kt & 1;
            if (kt < 63) {
                float2 v = *(const float2*)(hin + (size_t)((kt + 1) * 8 + skk) * 256 + r0 + srr);
                hs[cur ^ 1][srr][skk] = v.x; hs[cur ^ 1][srr + 1][skk] = v.y;
            }
            const float* hrow = &hs[cur][rl][0];
            float h8[8];
#pragma unroll
            for (int j = 0; j < 8; ++j) h8[j] = hrow[j];
#pragma unroll
            for (int uu = 0; uu < 2; ++uu)
#pragma unroll
                for (int g = 0; g < 3; ++g) {
                    const float* wp = &wlds[((usub * 2 + uu) * 3 + g) * 512 + kt * 8];
                    float4 w0 = *(const float4*)wp, w1 = *(const float4*)(wp + 4);
                    acc[uu][g] += h8[0]*w0.x + h8[1]*w0.y + h8[2]*w0.z + h8[3]*w0.w
                                + h8[4]*w1.x + h8[5]*w1.y + h8[6]*w1.z + h8[7]*w1.w;
                }
            __syncthreads();
        }
#pragma unroll
        for (int uu = 0; uu < 2; ++uu) {
            int ug = ub * 8 + usub * 2 + uu;
            size_t cbase = (size_t)st * 256 + r;
            float gr = gxT[(size_t)(       ug) * 4096 + cbase];
            float gz = gxT[(size_t)( 512 + ug) * 4096 + cbase];
            float gn = gxT[(size_t)(1024 + ug) * 4096 + cbase];
            float hold = hin[(size_t)ug * 256 + r];
            float rg = sigmoidf_(gr + acc[uu][0] + bh[uu][0]);
            float zg = sigmoidf_(gz + acc[uu][1] + bh[uu][1]);
            float ng = tanhf(gn + rg * (acc[uu][2] + bh[uu][2]));
            hout[(size_t)ug * 256 + r] = (1.f - zg) * ng + zg * hold;
        }
        grid.sync();
    }
}

// ---------------------------------------------------------------------------
__global__ void zerof(float* __restrict__ p, int n)
{
    int i = blockIdx.x * 256 + threadIdx.x;
    if (i < n) p[i] = 0.f;
}

__global__ void init_dec(float* __restrict__ hdec, u16* __restrict__ hbf, int* __restrict__ prev)
{
    int i = blockIdx.x * 256 + threadIdx.x;   // 262144
    hdec[i] = 0.f; hbf[i] = 0;
    if (i < B_) prev[i] = SOS_;
}

// hcat (torch h_n.view quirk): hcat[b][k] = h_dir(b>>7)[(2b)&255 + (k>>9)][k&511]
__global__ void hcat_build(const float* __restrict__ hT, float* __restrict__ hcat)
{
    int idx = blockIdx.x * 256 + threadIdx.x; // 262144
    int b = idx >> 10, k = idx & 1023;
    int d = b >> 7;
    int rr = ((2 * b) & 255) + (k >> 9);
    int kk = k & 511;
    hcat[idx] = hT[(size_t)d * (2 * 512 * 256) + (size_t)kk * 256 + rr];
}

// ---------------------------------------------------------------------------
// Decoder gh + gi GEMMs fused into ONE launch (fills the machine; they were
// serializing in-stream).  grid (48, 8): blockIdx.y<4 -> gh (A=hdec, K=1024,
// B=dwhh, +dbhh[n]); else -> gi (A=emb[prev], K=512, B=dwih[:, :512], +gctx).
// 64x64 tile, 4x4 per thread, BK=32.
// ---------------------------------------------------------------------------
__launch_bounds__(256)
__global__ void dec_gemm2(const float* __restrict__ hdec, const int* __restrict__ prev,
                          const float* __restrict__ emb,
                          const float* __restrict__ dwhh, const float* __restrict__ dwih,
                          const float* __restrict__ dbhh, const float* __restrict__ gctx,
                          float* __restrict__ ghbuf, float* __restrict__ gibuf)
{
    constexpr int BK = 32;
    __shared__ float As[BK][68];
    __shared__ float Bs[BK][68];
    const int t  = threadIdx.x;
    const int tx = t & 15, ty = t >> 4;
    const bool isH = blockIdx.y < 4;
    const int m_base = (isH ? blockIdx.y : (blockIdx.y - 4)) * 64;
    const int n_base = blockIdx.x * 64;
    const int K   = isH ? 1024 : 512;
    const float* Bp = isH ? dwhh : dwih;
    const int ldb  = isH ? 1024 : 1600;
    float* Cp = isH ? ghbuf : gibuf;

    float acc[4][4];
#pragma unroll
    for (int i = 0; i < 4; ++i)
#pragma unroll
        for (int j = 0; j < 4; ++j) acc[i][j] = 0.f;

    for (int k0 = 0; k0 < K; k0 += BK) {
#pragma unroll
        for (int j = 0; j < 2; ++j) {
            int f   = t + j * 256;
            int row = f >> 3;
            int kk  = (f & 7) << 2;
            int m   = m_base + row;
            float4 v;
            if (isH) v = ld4(hdec + (size_t)m * HID_ + k0 + kk);
            else     v = ld4(emb + (size_t)prev[m] * EMB_ + k0 + kk);
            As[kk + 0][row] = v.x; As[kk + 1][row] = v.y;
            As[kk + 2][row] = v.z; As[kk + 3][row] = v.w;
            float4 w = ld4(Bp + (size_t)(n_base + row) * ldb + k0 + kk);
            Bs[kk + 0][row] = w.x; Bs[kk + 1][row] = w.y;
            Bs[kk + 2][row] = w.z; Bs[kk + 3][row] = w.w;
        }
        __syncthreads();
#pragma unroll
        for (int kk = 0; kk < BK; ++kk) {
            float a[4], b[4];
            *(float4*)&a[0] = ld4(&As[kk][ty * 4]);
            *(float4*)&b[0] = ld4(&Bs[kk][tx * 4]);
#pragma unroll
            for (int i = 0; i < 4; ++i)
#pragma unroll
                for (int j = 0; j < 4; ++j) acc[i][j] += a[i] * b[j];
        }
        __syncthreads();
    }
#pragma unroll
    for (int i = 0; i < 4; ++i) {
        int m = m_base + ty * 4 + i;
#pragma unroll
        for (int j = 0; j < 4; ++j) {
            int n = n_base + tx * 4 + j;
            float v = acc[i][j];
            if (isH) v += dbhh[n];
            else     v += gctx[(size_t)m * 3072 + n];
            Cp[(size_t)m * 3072 + n] = v;
        }
    }
}

__global__ void dec_combine(const float* __restrict__ gi, const float* __restrict__ gh,
                            float* __restrict__ hdec, u16* __restrict__ hbf)
{
    int idx = blockIdx.x * 256 + threadIdx.x;  // 262144
    int b = idx >> 10, u = idx & 1023;
    size_t gb = (size_t)b * 3072;
    float r = sigmoidf_(gi[gb + u]            + gh[gb + u]);
    float z = sigmoidf_(gi[gb + HID_ + u]     + gh[gb + HID_ + u]);
    float n = tanhf    (gi[gb + 2 * HID_ + u] + r * gh[gb + 2 * HID_ + u]);
    float v = (1.f - z) * n + z * hdec[idx];
    hdec[idx] = v;
    hbf[idx] = f2bf(v);
}

// ---------------------------------------------------------------------------
// Fused bf16 MFMA logits + per-row softmax/top2 partials. No logits buffer.
// SINGLE m-pass: BM=256 (all rows), BN=128, 512 threads = 8 waves (4m x 2n).
// wout fp32 is now read ONCE per step (was twice) and converted once.
// Per row x 64-col half: (max, sumexp, top2 val/idx) partials, 500/row.
// ---------------------------------------------------------------------------
__launch_bounds__(512)
__global__ void gemm_logits(const u16* __restrict__ A, const float* __restrict__ Wf,
                            const float* __restrict__ bias,
                            float* __restrict__ pmax, float* __restrict__ psum,
                            float* __restrict__ ptv, int* __restrict__ pti)
{
    __shared__ u16 As[256][72];
    __shared__ u16 Bs[128][72];
    const int t = threadIdx.x;
    const int lane = t & 63, wave = t >> 6;
    const int wm = (wave & 3) * 64, wn = (wave >> 2) * 64;
    const int n0 = blockIdx.x * 128;
    f32x4 acc[4][4];
#pragma unroll
    for (int i = 0; i < 4; ++i)
#pragma unroll
        for (int j = 0; j < 4; ++j) acc[i][j] = (f32x4){0.f, 0.f, 0.f, 0.f};
    const int arow = t >> 1, aoff = (t & 1) * 32;
    const int brow = t >> 2, boff = (t & 3) * 16;

    for (int k0 = 0; k0 < 1024; k0 += 64) {
#pragma unroll
        for (int q = 0; q < 4; ++q) {
            *(uint4*)&As[arow][aoff + q * 8] =
                *(const uint4*)(A + (size_t)arow * 1024 + k0 + aoff + q * 8);
        }
        const float* wr = Wf + (size_t)(n0 + brow) * 1024 + k0 + boff;
#pragma unroll
        for (int q = 0; q < 2; ++q) {
            float4 x = ld4(wr + q * 8);
            float4 y = ld4(wr + q * 8 + 4);
            uint4 o;
            o.x = pk2(x.x, x.y); o.y = pk2(x.z, x.w);
            o.z = pk2(y.x, y.y); o.w = pk2(y.z, y.w);
            *(uint4*)&Bs[brow][boff + q * 8] = o;
        }
        __syncthreads();
#pragma unroll
        for (int s = 0; s < 2; ++s) {
            short8 a[4], b[4];
            int j0 = s * 32 + (lane >> 4) * 8;
#pragma unroll
            for (int i = 0; i < 4; ++i) {
                a[i] = *(const short8*)&As[wm + i * 16 + (lane & 15)][j0];
                b[i] = *(const short8*)&Bs[wn + i * 16 + (lane & 15)][j0];
            }
#pragma unroll
            for (int i = 0; i < 4; ++i)
#pragma unroll
                for (int j = 0; j < 4; ++j)
                    acc[i][j] = __builtin_amdgcn_mfma_f32_16x16x32_bf16(a[i], b[j], acc[i][j], 0, 0, 0);
        }
        __syncthreads();
    }

    // ---- fused epilogue: per-row (max, sumexp, top2) over this wave's 64 cols
    const int htile = blockIdx.x * 2 + (wn >> 6);
    float bn[4]; int jx[4];
#pragma unroll
    for (int j = 0; j < 4; ++j) { jx[j] = n0 + wn + j * 16 + (lane & 15); bn[j] = bias[jx[j]]; }
#pragma unroll
    for (int i = 0; i < 4; ++i) {
#pragma unroll
        for (int rr = 0; rr < 4; ++rr) {
            float v[4];
#pragma unroll
            for (int j = 0; j < 4; ++j) v[j] = acc[i][j][rr] + bn[j];
            float v1 = v[0], v2 = -3.4e38f; int i1 = jx[0], i2 = 0x7fffffff;
#pragma unroll
            for (int j = 1; j < 4; ++j) {
                if (v[j] > v1)      { v2 = v1; i2 = i1; v1 = v[j]; i1 = jx[j]; }
                else if (v[j] > v2) { v2 = v[j]; i2 = jx[j]; }
            }
#pragma unroll
            for (int mask = 1; mask <= 8; mask <<= 1) {
                float ov1 = __shfl_xor(v1, mask), ov2 = __shfl_xor(v2, mask);
                int   oi1 = __shfl_xor(i1, mask), oi2 = __shfl_xor(i2, mask);
                merge_top2(v1, i1, v2, i2, ov1, oi1, ov2, oi2);
            }
            float rmax = v1;
            float s = 0.f;
#pragma unroll
            for (int j = 0; j < 4; ++j) s += expf(v[j] - rmax);
#pragma unroll
            for (int mask = 1; mask <= 8; mask <<= 1) s += __shfl_xor(s, mask);
            if ((lane & 15) == 0) {
                int row = wm + i * 16 + (lane >> 4) * 4 + rr;
                size_t base = (size_t)row * 500 + htile;
                pmax[base] = rmax; psum[base] = s;
                ptv[base * 2] = v1; ptv[base * 2 + 1] = v2;
                pti[base * 2] = i1; pti[base * 2 + 1] = i2;
            }
        }
    }
}

// ---------------------------------------------------------------------------
// Per-row combine of 500 half-tile partials: global max/sumexp, top-8 from
// 1000 candidates, exact fp32 rescore (first-index tie-break), token + lp.
// ---------------------------------------------------------------------------
__launch_bounds__(256)
__global__ void dec_reduce(const float* __restrict__ pmax, const float* __restrict__ psum,
                           const float* __restrict__ ptv, const int* __restrict__ pti,
                           const float* __restrict__ hdec, const float* __restrict__ wout,
                           const float* __restrict__ bout,
                           float* __restrict__ out, int* __restrict__ prev, int tstep)
{
    __shared__ float sv[256]; __shared__ int sti[256]; __shared__ int ssl[256];
    __shared__ float cvv[1000]; __shared__ int cii[1000];
    __shared__ float c8v[8]; __shared__ int c8i[8]; __shared__ float c8e[8];
    const int b = blockIdx.x, tid = threadIdx.x;
    const float* pm = pmax + (size_t)b * 500;
    const float* ps = psum + (size_t)b * 500;

    float m = -3.4e38f;
    for (int i = tid; i < 500; i += 256) m = fmaxf(m, pm[i]);
    sv[tid] = m; __syncthreads();
    for (int off = 128; off; off >>= 1) { if (tid < off) sv[tid] = fmaxf(sv[tid], sv[tid + off]); __syncthreads(); }
    float gmax = sv[0]; __syncthreads();

    float s = 0.f;
    for (int i = tid; i < 500; i += 256) s += ps[i] * expf(pm[i] - gmax);
    sv[tid] = s; __syncthreads();
    for (int off = 128; off; off >>= 1) { if (tid < off) sv[tid] += sv[tid + off]; __syncthreads(); }
    float gsum = sv[0]; __syncthreads();

    for (int i = tid; i < 1000; i += 256) { cvv[i] = ptv[(size_t)b * 1000 + i]; cii[i] = pti[(size_t)b * 1000 + i]; }
    __syncthreads();

    for (int c = 0; c < 8; ++c) {
        float bv = -3.4e38f; int bi = 0x7fffffff, bs = 0;
        for (int i = tid; i < 1000; i += 256) {
            float v = cvv[i]; int ix = cii[i];
            if (v > bv || (v == bv && ix < bi)) { bv = v; bi = ix; bs = i; }
        }
        sv[tid] = bv; sti[tid] = bi; ssl[tid] = bs; __syncthreads();
        for (int off = 128; off; off >>= 1) {
            if (tid < off) {
                if (sv[tid + off] > sv[tid] ||
                    (sv[tid + off] == sv[tid] && sti[tid + off] < sti[tid])) {
                    sv[tid] = sv[tid + off]; sti[tid] = sti[tid + off]; ssl[tid] = ssl[tid + off];
                }
            }
            __syncthreads();
        }
        if (tid == 0) { c8v[c] = sv[0]; c8i[c] = sti[0]; cvv[ssl[0]] = -3.4e38f; }
        __syncthreads();
    }

    {   // exact fp32 rescore, 2 candidates per wave
        int lane = tid & 63, wv = tid >> 6;
        const float* hr = hdec + (size_t)b * HID_;
        for (int c = wv; c < 8; c += 4) {
            const float* wr = wout + (size_t)c8i[c] * HID_;
            float a = 0.f;
            for (int k = lane * 4; k < HID_; k += 256) {
                float4 x = ld4(hr + k), y = ld4(wr + k);
                a += x.x * y.x + x.y * y.y + x.z * y.z + x.w * y.w;
            }
#pragma unroll
            for (int off = 32; off; off >>= 1) a += __shfl_down(a, off);
            if (lane == 0) c8e[c] = a + bout[c8i[c]];
        }
    }
    __syncthreads();

    if (tid == 0) {
        float bv = c8e[0]; int bi = c8i[0]; float av = c8v[0];
        for (int c = 1; c < 8; ++c)
            if (c8e[c] > bv || (c8e[c] == bv && c8i[c] < bi)) { bv = c8e[c]; bi = c8i[c]; av = c8v[c]; }
        float p = expf(av - gmax) / gsum;
        float lp = logf(p + 1e-12f);
        out[(size_t)b * TMAX_ + tstep] = (float)bi;
        out[B_ * TMAX_ + (size_t)b * TMAX_ + tstep] = lp;
        prev[b] = bi;
    }
}

// ---------------------------------------------------------------------------
extern "C" void kernel_launch(void* const* d_in, const int* in_sizes, int n_in,
                              void* d_out, int out_size, void* d_ws, size_t ws_size,
                              hipStream_t stream)
{
    const int*   ids   = (const int*)  d_in[0];
    const float* cvec  = (const float*)d_in[1];
    const float* emb   = (const float*)d_in[2];
    const float* wih_f = (const float*)d_in[3];
    const float* whh_f = (const float*)d_in[4];
    const float* bih_f = (const float*)d_in[5];
    const float* bhh_f = (const float*)d_in[6];
    const float* wih_b = (const float*)d_in[7];
    const float* whh_b = (const float*)d_in[8];
    const float* bih_b = (const float*)d_in[9];
    const float* bhh_b = (const float*)d_in[10];
    const float* dwih  = (const float*)d_in[11];
    const float* dwhh  = (const float*)d_in[12];
    const float* dbih  = (const float*)d_in[13];
    const float* dbhh  = (const float*)d_in[14];
    const float* wout  = (const float*)d_in[15];
    const float* bout  = (const float*)d_in[16];
    float* out = (float*)d_out;

    // workspace carve (floats); persistent total = 14,549,248 f = 58.2 MB
    // (<= 68 MB proven).  Decoder scratch aliases the gxT_f region, which is
    // dead once the encoder finishes.
    float* w      = (float*)d_ws;
    float* gxT_f  = w;                          // 6,291,456 (16 steps)
    float* gxT_b  = w + 6291456;                // 6,291,456
    float* hT     = w + 12582912;               // 524,288
    float* hcat   = w + 13107200;               // 262,144
    float* hdec   = w + 13369344;               // 262,144
    float* gctx   = w + 13631488;               // 786,432
    u16*   hdecb  = (u16*)(w + 14417920);       // 131,072 f
    int*   prev   = (int*)(w + 14548992);       // 256
    // --- decoder-phase aliases over gxT_f (needs 2,340,864 of 6,291,456) ---
    float* gibuf  = gxT_f;                      // 786,432
    float* ghbuf  = gxT_f + 786432;             // 786,432
    float* pmax   = gxT_f + 1572864;            // 128,000
    float* psum   = gxT_f + 1700864;            // 128,000
    float* ptv    = gxT_f + 1828864;            // 256,000
    int*   pti    = (int*)(gxT_f + 2084864);    // 256,000

    zerof<<<2048, 256, 0, stream>>>(hT, 524288);
    init_dec<<<1024, 256, 0, stream>>>(hdec, hdecb, prev);

    // ---------------- encoder: 8 chunks x 16 steps, both dirs in-kernel ----------------
    for (int c = 0; c < 8; ++c) {
        enc_gx<<<dim3(32, 12, 2), 256, 0, stream>>>(
            wih_f, wih_b, bih_f, bih_b, ids, emb, gxT_f, gxT_b, c);
        int nsteps = 16;
        void* args[] = { &gxT_f, &gxT_b, &whh_f, &whh_b, &bhh_f, &bhh_b, &hT, &nsteps };
        hipLaunchCooperativeKernel(reinterpret_cast<void*>(enc_coop),
                                   dim3(256), dim3(512), args, 0, stream);
    }

    hcat_build<<<1024, 256, 0, stream>>>(hT, hcat);

    // gctx[b][3072] = [hcat|cvec] @ dec_wih[:,512:1600]^T + dbih
    gemm_nt<64, 64, 4, 4, 2, 0, 0><<<dim3(48, 4), 256, 0, stream>>>(
        hcat, nullptr, cvec, dwih, 1600, 512, dbih, nullptr,
        gctx, 3072, 1024, 1088, 0, 0);

    // ---------------- decoder: 40 greedy steps ----------------
    for (int t = 0; t < TMAX_; ++t) {
        dec_gemm2<<<dim3(48, 8), 256, 0, stream>>>(
            hdec, prev, emb, dwhh, dwih, dbhh, gctx, ghbuf, gibuf);
        dec_combine<<<1024, 256, 0, stream>>>(gibuf, ghbuf, hdec, hdecb);
        gemm_logits<<<dim3(250, 1), 512, 0, stream>>>(hdecb, wout, bout,
                                                      pmax, psum, ptv, pti);
        dec_reduce<<<256, 256, 0, stream>>>(pmax, psum, ptv, pti,
                                            hdec, wout, bout, out, prev, t);
    }
}

// Round 2
// 11457.456 us; speedup vs baseline: 1.5744x; 1.3363x over previous
//
#include <hip/hip_runtime.h>
#include <hip/hip_bf16.h>
#include <math.h>

#define B_    256
#define S_    128
#define EMB_  512
#define H2_   512
#define HID_  1024
#define CTX_  64
#define VOC_  32000
#define TMAX_ 40
#define SOS_  2

typedef unsigned short u16;
typedef __attribute__((ext_vector_type(8))) short short8;
typedef __attribute__((ext_vector_type(4))) float f32x4;

__device__ __forceinline__ float4 ld4(const float* p) {
    return *reinterpret_cast<const float4*>(p);
}
__device__ __forceinline__ float sigmoidf_(float x) { return 1.f / (1.f + expf(-x)); }
__device__ __forceinline__ u16 f2bf(float x) {
    union { float f; unsigned int u; } v; v.f = x;
    unsigned int r = v.u + 0x7FFFu + ((v.u >> 16) & 1u);
    return (u16)(r >> 16);
}
__device__ __forceinline__ unsigned pk2(float a, float b) {
    float2 t; t.x = a; t.y = b;
    __hip_bfloat162 h = __float22bfloat162_rn(t);
    return *reinterpret_cast<unsigned*>(&h);
}
// merge two (value desc, index asc)-ordered top-2 pairs
__device__ __forceinline__ void merge_top2(float& v1, int& i1, float& v2, int& i2,
                                           float ov1, int oi1, float ov2, int oi2)
{
    if (ov1 > v1 || (ov1 == v1 && oi1 < i1)) {
        float tv = v1; int ti = i1;
        v1 = ov1; i1 = oi1;
        if (ov2 > tv || (ov2 == tv && oi2 < ti)) { v2 = ov2; i2 = oi2; }
        else                                     { v2 = tv;  i2 = ti;  }
    } else {
        if (ov1 > v2 || (ov1 == v2 && oi1 < i2)) { v2 = ov1; i2 = oi1; }
    }
}

// ---------------------------------------------------------------------------
// fp32 tiled GEMM (kept for the one-shot gctx GEMM):
// C[m][n] = sum_k A[m][k]*B[n][k] (+bias) (+addsrc)
// AMODE: 0 plain A (lda) | 2 decoder-ctx composite | 3 emb gather via ids[m]
// BIASM: 0 -> bias[n], 1 -> bias[m]
// ---------------------------------------------------------------------------
template<int BM, int BN, int TM, int TN, int AMODE, int BGATHER, int BIASM>
__launch_bounds__(256)
__global__ void gemm_nt(const float* __restrict__ Ap,
                        const int*   __restrict__ ids,
                        const float* __restrict__ Ex,
                        const float* __restrict__ Bp, int ldb, int bofs,
                        const float* __restrict__ bias,
                        const float* __restrict__ addsrc,
                        float* __restrict__ Cp, int ldc,
                        int lda, int K, int s_base, int sdir)
{
    constexpr int BK = 32;
    __shared__ float As[BK][BM + 4];
    __shared__ float Bs[BK][BN + 4];
    const int t  = threadIdx.x;
    const int tx = t & 15, ty = t >> 4;
    const int m_base = blockIdx.y * BM;
    const int n_base = blockIdx.x * BN;

    float acc[TM][TN];
#pragma unroll
    for (int i = 0; i < TM; ++i)
#pragma unroll
        for (int j = 0; j < TN; ++j) acc[i][j] = 0.f;

    constexpr int A_PER = BM * BK / 4 / 256;
    constexpr int B_PER = BN * BK / 4 / 256;

    for (int k0 = 0; k0 < K; k0 += BK) {
#pragma unroll
        for (int j = 0; j < A_PER; ++j) {
            int f   = t + j * 256;
            int row = f >> 3;
            int kk  = (f & 7) << 2;
            int m   = m_base + row;
            float4 v;
            if constexpr (AMODE == 0) {
                v = ld4(Ap + (size_t)m * lda + k0 + kk);
            } else if constexpr (AMODE == 3) {
                int id = ids[m];
                v = ld4(Ex + (size_t)id * EMB_ + k0 + kk);
            } else {  // AMODE == 2
                int k = k0 + kk;
                if (k < HID_) v = ld4(Ap + (size_t)m * HID_ + k);
                else          v = ld4(Ex + (size_t)m * CTX_ + (k - HID_));
            }
            As[kk + 0][row] = v.x; As[kk + 1][row] = v.y;
            As[kk + 2][row] = v.z; As[kk + 3][row] = v.w;
        }
#pragma unroll
        for (int j = 0; j < B_PER; ++j) {
            int f   = t + j * 256;
            int row = f >> 3;
            int kk  = (f & 7) << 2;
            float4 v;
            if constexpr (BGATHER == 1) {
                int n = n_base + row;
                int s = n >> 8, b = n & 255;
                int id = ids[b * S_ + s_base + sdir * s];
                v = ld4(Ex + (size_t)id * EMB_ + k0 + kk);
            } else {
                v = ld4(Bp + (size_t)(n_base + row) * ldb + bofs + k0 + kk);
            }
            Bs[kk + 0][row] = v.x; Bs[kk + 1][row] = v.y;
            Bs[kk + 2][row] = v.z; Bs[kk + 3][row] = v.w;
        }
        __syncthreads();
#pragma unroll
        for (int kk = 0; kk < BK; ++kk) {
            float a[TM], b[TN];
            *(float4*)&a[0] = ld4(&As[kk][ty * TM]);
            if constexpr (TM == 8) *(float4*)&a[4] = ld4(&As[kk][ty * TM + 4]);
            *(float4*)&b[0] = ld4(&Bs[kk][tx * TN]);
            if constexpr (TN == 8) *(float4*)&b[4] = ld4(&Bs[kk][tx * TN + 4]);
#pragma unroll
            for (int i = 0; i < TM; ++i)
#pragma unroll
                for (int j = 0; j < TN; ++j) acc[i][j] += a[i] * b[j];
        }
        __syncthreads();
    }
#pragma unroll
    for (int i = 0; i < TM; ++i) {
        int m = m_base + ty * TM + i;
#pragma unroll
        for (int j = 0; j < TN; ++j) {
            int n = n_base + tx * TN + j;
            float v = acc[i][j];
            if (bias) v += BIASM ? bias[m] : bias[n];
            if (addsrc) v += addsrc[(size_t)m * ldc + n];
            Cp[(size_t)m * ldc + n] = v;
        }
    }
}

// ---------------------------------------------------------------------------
// Encoder gx GEMM, both dirs in one launch (blockIdx.z = dir), TRANSPOSED
// output: gx[s*256+b][col] = emb[ids] @ wih^T + bih[col].
// M = 4096 rows (16 steps x 256 batch, gathered emb), N = 1536 cols, K = 512.
// grid (12, 32, 2), 128x128 tiles, 8x8 per thread.
// ---------------------------------------------------------------------------
__launch_bounds__(256)
__global__ void enc_gx2(const float* __restrict__ wih_f, const float* __restrict__ wih_b,
                        const float* __restrict__ bih_f, const float* __restrict__ bih_b,
                        const int* __restrict__ ids, const float* __restrict__ emb,
                        float* __restrict__ gx_f, float* __restrict__ gx_b, int c)
{
    constexpr int BK = 32;
    __shared__ float As[BK][132];
    __shared__ float Bs[BK][132];
    const int t  = threadIdx.x;
    const int tx = t & 15, ty = t >> 4;
    const int dz = blockIdx.z;
    const float* W    = dz ? wih_b : wih_f;
    const float* bias = dz ? bih_b : bih_f;
    float*       Cp   = dz ? gx_b : gx_f;
    const int s_base  = dz ? (127 - 16 * c) : (16 * c);
    const int sdir    = dz ? -1 : 1;
    const int m_base = blockIdx.y * 128;
    const int n_base = blockIdx.x * 128;

    float acc[8][8];
#pragma unroll
    for (int i = 0; i < 8; ++i)
#pragma unroll
        for (int j = 0; j < 8; ++j) acc[i][j] = 0.f;

    for (int k0 = 0; k0 < 512; k0 += BK) {
#pragma unroll
        for (int j = 0; j < 4; ++j) {
            int f   = t + j * 256;
            int row = f >> 3;
            int kk  = (f & 7) << 2;
            int m   = m_base + row;
            int s   = m >> 8, b = m & 255;
            int id  = ids[b * S_ + s_base + sdir * s];
            float4 v = ld4(emb + (size_t)id * EMB_ + k0 + kk);
            As[kk + 0][row] = v.x; As[kk + 1][row] = v.y;
            As[kk + 2][row] = v.z; As[kk + 3][row] = v.w;
        }
#pragma unroll
        for (int j = 0; j < 4; ++j) {
            int f   = t + j * 256;
            int row = f >> 3;
            int kk  = (f & 7) << 2;
            float4 v = ld4(W + (size_t)(n_base + row) * 512 + k0 + kk);
            Bs[kk + 0][row] = v.x; Bs[kk + 1][row] = v.y;
            Bs[kk + 2][row] = v.z; Bs[kk + 3][row] = v.w;
        }
        __syncthreads();
#pragma unroll
        for (int kk = 0; kk < BK; ++kk) {
            float a[8], b[8];
            *(float4*)&a[0] = ld4(&As[kk][ty * 8]);
            *(float4*)&a[4] = ld4(&As[kk][ty * 8 + 4]);
            *(float4*)&b[0] = ld4(&Bs[kk][tx * 8]);
            *(float4*)&b[4] = ld4(&Bs[kk][tx * 8 + 4]);
#pragma unroll
            for (int i = 0; i < 8; ++i)
#pragma unroll
                for (int j = 0; j < 8; ++j) acc[i][j] += a[i] * b[j];
        }
        __syncthreads();
    }
#pragma unroll
    for (int i = 0; i < 8; ++i) {
        int m = m_base + ty * 8 + i;
#pragma unroll
        for (int j = 0; j < 8; ++j) {
            int n = n_base + tx * 8 + j;
            Cp[(size_t)m * 1536 + n] = acc[i][j] + bias[n];
        }
    }
}

// ---------------------------------------------------------------------------
// whh transpose/interleave: whhX[k][u*3+g] = whh[g*512+u][k].  One-time.
// ---------------------------------------------------------------------------
__global__ void whh_trans(const float* __restrict__ whh_f, const float* __restrict__ whh_b,
                          float* __restrict__ whhX_f, float* __restrict__ whhX_b)
{
    int idx = blockIdx.x * 256 + threadIdx.x;        // [0, 786432)
    const float* src = blockIdx.y ? whh_b : whh_f;
    float*       dst = blockIdx.y ? whhX_b : whhX_f;
    int k  = idx / 1536;
    int cc = idx - k * 1536;
    int u  = cc / 3;
    int g  = cc - u * 3;
    dst[idx] = src[(size_t)(g * 512 + u) * 512 + k];
}

// ---------------------------------------------------------------------------
// Batch-parallel encoder recurrence: NO grid syncs.  128 blocks x 512 thr.
// Block owns (dir, 4 batch rows); full 512-unit h lives in LDS across the
// 16-step chunk.  whhX streamed from (XCD-local) L2 each step.  Thread t:
// kh = t>>8 (k half), tu = t&255 -> units 2tu, 2tu+1; k-halves combined via
// LDS.  dir is placed by XCD (blockIdx%8): XCD 0-3 -> fwd, 4-7 -> bwd, so
// each XCD's 4MB L2 caches exactly one 3MB whhX image.
// gx layout: [st][row][1536]; hT layout: [dir][row 256][unit 512].
// ---------------------------------------------------------------------------
__launch_bounds__(512)
__global__ void enc_rec(const float* __restrict__ gxc_f, const float* __restrict__ gxc_b,
                        const float* __restrict__ whhX_f, const float* __restrict__ whhX_b,
                        const float* __restrict__ bhh_f, const float* __restrict__ bhh_b,
                        float* __restrict__ hT, int nsteps)
{
    __shared__ __align__(16) float hbuf[2][512][4];   // 16 KB: [buf][unit][row]
    __shared__ float red[256][25];                    // 25.6 KB k-half partials
    const int bid = blockIdx.x;
    const int xcd = bid & 7;
    const int dir = xcd >> 2;
    const int local = (bid >> 3) * 4 + (xcd & 3);     // [0,64)
    const int r0 = local * 4;
    const float* gx  = dir ? gxc_b : gxc_f;
    const float* whx = dir ? whhX_b : whhX_f;
    const float* bhh = dir ? bhh_b : bhh_f;
    float* hTd = hT + (size_t)dir * (256 * 512);

    const int t  = threadIdx.x;
    const int kh = t >> 8;          // k half: 0 -> k in [0,256), 1 -> [256,512)
    const int tu = t & 255;         // unit pair: units 2tu, 2tu+1
    const int k_base = kh << 8;

    // load h (4 rows x 512 units) into hbuf[0][u][r]
    for (int i = t; i < 2048; i += 512) {
        int r = i >> 9, u = i & 511;
        hbuf[0][u][r] = hTd[(size_t)(r0 + r) * 512 + u];
    }
    float bh[2][3];
#pragma unroll
    for (int uu = 0; uu < 2; ++uu)
#pragma unroll
        for (int g = 0; g < 3; ++g)
            bh[uu][g] = bhh[g * 512 + tu * 2 + uu];
    __syncthreads();

    for (int st = 0; st < nsteps; ++st) {
        const int cur = st & 1, nxt = cur ^ 1;
        float acc[2][3][4];
#pragma unroll
        for (int uu = 0; uu < 2; ++uu)
#pragma unroll
            for (int g = 0; g < 3; ++g)
#pragma unroll
                for (int r = 0; r < 4; ++r) acc[uu][g][r] = 0.f;

        const float* wp = whx + (size_t)k_base * 1536 + tu * 6;
#pragma unroll 4
        for (int kk = 0; kk < 256; ++kk) {
            float4 hv = *(const float4*)&hbuf[cur][k_base + kk][0];
            float2 w0 = *(const float2*)(wp + 0);   // (u0,r) (u0,z)
            float2 w1 = *(const float2*)(wp + 2);   // (u0,n) (u1,r)
            float2 w2 = *(const float2*)(wp + 4);   // (u1,z) (u1,n)
            const float* hvp = (const float*)&hv;
#pragma unroll
            for (int r = 0; r < 4; ++r) {
                float h = hvp[r];
                acc[0][0][r] += w0.x * h;
                acc[0][1][r] += w0.y * h;
                acc[0][2][r] += w1.x * h;
                acc[1][0][r] += w1.y * h;
                acc[1][1][r] += w2.x * h;
                acc[1][2][r] += w2.y * h;
            }
            wp += 1536;
        }

        if (kh) {
#pragma unroll
            for (int uu = 0; uu < 2; ++uu)
#pragma unroll
                for (int g = 0; g < 3; ++g)
#pragma unroll
                    for (int r = 0; r < 4; ++r)
                        red[tu][(uu * 3 + g) * 4 + r] = acc[uu][g][r];
        }
        __syncthreads();
        if (!kh) {
#pragma unroll
            for (int uu = 0; uu < 2; ++uu)
#pragma unroll
                for (int g = 0; g < 3; ++g)
#pragma unroll
                    for (int r = 0; r < 4; ++r)
                        acc[uu][g][r] += red[tu][(uu * 3 + g) * 4 + r];
            float2 gxv[3][4];
#pragma unroll
            for (int g = 0; g < 3; ++g)
#pragma unroll
                for (int r = 0; r < 4; ++r)
                    gxv[g][r] = *(const float2*)&gx[(size_t)((st << 8) + r0 + r) * 1536
                                                    + (g << 9) + (tu << 1)];
#pragma unroll
            for (int uu = 0; uu < 2; ++uu) {
                int u = tu * 2 + uu;
#pragma unroll
                for (int r = 0; r < 4; ++r) {
                    float gr = uu ? gxv[0][r].y : gxv[0][r].x;
                    float gz = uu ? gxv[1][r].y : gxv[1][r].x;
                    float gn = uu ? gxv[2][r].y : gxv[2][r].x;
                    float hold = hbuf[cur][u][r];
                    float rg = sigmoidf_(gr + acc[uu][0][r] + bh[uu][0]);
                    float zg = sigmoidf_(gz + acc[uu][1][r] + bh[uu][1]);
                    float ng = tanhf(gn + rg * (acc[uu][2][r] + bh[uu][2]));
                    hbuf[nxt][u][r] = (1.f - zg) * ng + zg * hold;
                }
            }
        }
        __syncthreads();
    }

    const int lb = nsteps & 1;
    for (int i = t; i < 2048; i += 512) {
        int r = i >> 9, u = i & 511;
        hTd[(size_t)(r0 + r) * 512 + u] = hbuf[lb][u][r];
    }
}

// ---------------------------------------------------------------------------
__global__ void zerof(float* __restrict__ p, int n)
{
    int i = blockIdx.x * 256 + threadIdx.x;
    if (i < n) p[i] = 0.f;
}

__global__ void init_dec(float* __restrict__ hdec, u16* __restrict__ hbf, int* __restrict__ prev)
{
    int i = blockIdx.x * 256 + threadIdx.x;   // 262144
    hdec[i] = 0.f; hbf[i] = 0;
    if (i < B_) prev[i] = SOS_;
}

// hcat (torch h_n.view quirk): hcat[b][k] = h_dir(b>>7)[(2b)&255 + (k>>9)][k&511]
// hT layout: [dir][row 256][unit 512]
__global__ void hcat_build(const float* __restrict__ hT, float* __restrict__ hcat)
{
    int idx = blockIdx.x * 256 + threadIdx.x; // 262144
    int b = idx >> 10, k = idx & 1023;
    int d = b >> 7;
    int rr = ((2 * b) & 255) + (k >> 9);
    int kk = k & 511;
    hcat[idx] = hT[(size_t)d * 131072 + (size_t)rr * 512 + kk];
}

// ---------------------------------------------------------------------------
// Decoder gh + gi GEMMs fused into ONE launch.  grid (48, 8): blockIdx.y<4 ->
// gh (A=hdec, K=1024, B=dwhh, +dbhh[n]); else -> gi (A=emb[prev], K=512,
// B=dwih[:, :512], +gctx).  64x64 tile, 4x4 per thread, BK=32.
// ---------------------------------------------------------------------------
__launch_bounds__(256)
__global__ void dec_gemm2(const float* __restrict__ hdec, const int* __restrict__ prev,
                          const float* __restrict__ emb,
                          const float* __restrict__ dwhh, const float* __restrict__ dwih,
                          const float* __restrict__ dbhh, const float* __restrict__ gctx,
                          float* __restrict__ ghbuf, float* __restrict__ gibuf)
{
    constexpr int BK = 32;
    __shared__ float As[BK][68];
    __shared__ float Bs[BK][68];
    const int t  = threadIdx.x;
    const int tx = t & 15, ty = t >> 4;
    const bool isH = blockIdx.y < 4;
    const int m_base = (isH ? blockIdx.y : (blockIdx.y - 4)) * 64;
    const int n_base = blockIdx.x * 64;
    const int K   = isH ? 1024 : 512;
    const float* Bp = isH ? dwhh : dwih;
    const int ldb  = isH ? 1024 : 1600;
    float* Cp = isH ? ghbuf : gibuf;

    float acc[4][4];
#pragma unroll
    for (int i = 0; i < 4; ++i)
#pragma unroll
        for (int j = 0; j < 4; ++j) acc[i][j] = 0.f;

    for (int k0 = 0; k0 < K; k0 += BK) {
#pragma unroll
        for (int j = 0; j < 2; ++j) {
            int f   = t + j * 256;
            int row = f >> 3;
            int kk  = (f & 7) << 2;
            int m   = m_base + row;
            float4 v;
            if (isH) v = ld4(hdec + (size_t)m * HID_ + k0 + kk);
            else     v = ld4(emb + (size_t)prev[m] * EMB_ + k0 + kk);
            As[kk + 0][row] = v.x; As[kk + 1][row] = v.y;
            As[kk + 2][row] = v.z; As[kk + 3][row] = v.w;
            float4 w = ld4(Bp + (size_t)(n_base + row) * ldb + k0 + kk);
            Bs[kk + 0][row] = w.x; Bs[kk + 1][row] = w.y;
            Bs[kk + 2][row] = w.z; Bs[kk + 3][row] = w.w;
        }
        __syncthreads();
#pragma unroll
        for (int kk = 0; kk < BK; ++kk) {
            float a[4], b[4];
            *(float4*)&a[0] = ld4(&As[kk][ty * 4]);
            *(float4*)&b[0] = ld4(&Bs[kk][tx * 4]);
#pragma unroll
            for (int i = 0; i < 4; ++i)
#pragma unroll
                for (int j = 0; j < 4; ++j) acc[i][j] += a[i] * b[j];
        }
        __syncthreads();
    }
#pragma unroll
    for (int i = 0; i < 4; ++i) {
        int m = m_base + ty * 4 + i;
#pragma unroll
        for (int j = 0; j < 4; ++j) {
            int n = n_base + tx * 4 + j;
            float v = acc[i][j];
            if (isH) v += dbhh[n];
            else     v += gctx[(size_t)m * 3072 + n];
            Cp[(size_t)m * 3072 + n] = v;
        }
    }
}

__global__ void dec_combine(const float* __restrict__ gi, const float* __restrict__ gh,
                            float* __restrict__ hdec, u16* __restrict__ hbf)
{
    int idx = blockIdx.x * 256 + threadIdx.x;  // 262144
    int b = idx >> 10, u = idx & 1023;
    size_t gb = (size_t)b * 3072;
    float r = sigmoidf_(gi[gb + u]            + gh[gb + u]);
    float z = sigmoidf_(gi[gb + HID_ + u]     + gh[gb + HID_ + u]);
    float n = tanhf    (gi[gb + 2 * HID_ + u] + r * gh[gb + 2 * HID_ + u]);
    float v = (1.f - z) * n + z * hdec[idx];
    hdec[idx] = v;
    hbf[idx] = f2bf(v);
}

// ---------------------------------------------------------------------------
// Fused bf16 MFMA logits + per-row softmax/top2 partials. No logits buffer.
// Single m-pass: BM=256 (all rows), BN=128, 512 threads = 8 waves (4m x 2n).
// Per row x 64-col half: (max, sumexp, top2 val/idx) partials, 500/row.
// ---------------------------------------------------------------------------
__launch_bounds__(512)
__global__ void gemm_logits(const u16* __restrict__ A, const float* __restrict__ Wf,
                            const float* __restrict__ bias,
                            float* __restrict__ pmax, float* __restrict__ psum,
                            float* __restrict__ ptv, int* __restrict__ pti)
{
    __shared__ u16 As[256][72];
    __shared__ u16 Bs[128][72];
    const int t = threadIdx.x;
    const int lane = t & 63, wave = t >> 6;
    const int wm = (wave & 3) * 64, wn = (wave >> 2) * 64;
    const int n0 = blockIdx.x * 128;
    f32x4 acc[4][4];
#pragma unroll
    for (int i = 0; i < 4; ++i)
#pragma unroll
        for (int j = 0; j < 4; ++j) acc[i][j] = (f32x4){0.f, 0.f, 0.f, 0.f};
    const int arow = t >> 1, aoff = (t & 1) * 32;
    const int brow = t >> 2, boff = (t & 3) * 16;

    for (int k0 = 0; k0 < 1024; k0 += 64) {
#pragma unroll
        for (int q = 0; q < 4; ++q) {
            *(uint4*)&As[arow][aoff + q * 8] =
                *(const uint4*)(A + (size_t)arow * 1024 + k0 + aoff + q * 8);
        }
        const float* wr = Wf + (size_t)(n0 + brow) * 1024 + k0 + boff;
#pragma unroll
        for (int q = 0; q < 2; ++q) {
            float4 x = ld4(wr + q * 8);
            float4 y = ld4(wr + q * 8 + 4);
            uint4 o;
            o.x = pk2(x.x, x.y); o.y = pk2(x.z, x.w);
            o.z = pk2(y.x, y.y); o.w = pk2(y.z, y.w);
            *(uint4*)&Bs[brow][boff + q * 8] = o;
        }
        __syncthreads();
#pragma unroll
        for (int s = 0; s < 2; ++s) {
            short8 a[4], b[4];
            int j0 = s * 32 + (lane >> 4) * 8;
#pragma unroll
            for (int i = 0; i < 4; ++i) {
                a[i] = *(const short8*)&As[wm + i * 16 + (lane & 15)][j0];
                b[i] = *(const short8*)&Bs[wn + i * 16 + (lane & 15)][j0];
            }
#pragma unroll
            for (int i = 0; i < 4; ++i)
#pragma unroll
                for (int j = 0; j < 4; ++j)
                    acc[i][j] = __builtin_amdgcn_mfma_f32_16x16x32_bf16(a[i], b[j], acc[i][j], 0, 0, 0);
        }
        __syncthreads();
    }

    // ---- fused epilogue: per-row (max, sumexp, top2) over this wave's 64 cols
    const int htile = blockIdx.x * 2 + (wn >> 6);
    float bn[4]; int jx[4];
#pragma unroll
    for (int j = 0; j < 4; ++j) { jx[j] = n0 + wn + j * 16 + (lane & 15); bn[j] = bias[jx[j]]; }
#pragma unroll
    for (int i = 0; i < 4; ++i) {
#pragma unroll
        for (int rr = 0; rr < 4; ++rr) {
            float v[4];
#pragma unroll
            for (int j = 0; j < 4; ++j) v[j] = acc[i][j][rr] + bn[j];
            float v1 = v[0], v2 = -3.4e38f; int i1 = jx[0], i2 = 0x7fffffff;
#pragma unroll
            for (int j = 1; j < 4; ++j) {
                if (v[j] > v1)      { v2 = v1; i2 = i1; v1 = v[j]; i1 = jx[j]; }
                else if (v[j] > v2) { v2 = v[j]; i2 = jx[j]; }
            }
#pragma unroll
            for (int mask = 1; mask <= 8; mask <<= 1) {
                float ov1 = __shfl_xor(v1, mask), ov2 = __shfl_xor(v2, mask);
                int   oi1 = __shfl_xor(i1, mask), oi2 = __shfl_xor(i2, mask);
                merge_top2(v1, i1, v2, i2, ov1, oi1, ov2, oi2);
            }
            float rmax = v1;
            float s = 0.f;
#pragma unroll
            for (int j = 0; j < 4; ++j) s += expf(v[j] - rmax);
#pragma unroll
            for (int mask = 1; mask <= 8; mask <<= 1) s += __shfl_xor(s, mask);
            if ((lane & 15) == 0) {
                int row = wm + i * 16 + (lane >> 4) * 4 + rr;
                size_t base = (size_t)row * 500 + htile;
                pmax[base] = rmax; psum[base] = s;
                ptv[base * 2] = v1; ptv[base * 2 + 1] = v2;
                pti[base * 2] = i1; pti[base * 2 + 1] = i2;
            }
        }
    }
}

// ---------------------------------------------------------------------------
// Per-row combine of 500 half-tile partials: global max/sumexp, top-8 from
// 1000 candidates, exact fp32 rescore (first-index tie-break), token + lp.
// ---------------------------------------------------------------------------
__launch_bounds__(256)
__global__ void dec_reduce(const float* __restrict__ pmax, const float* __restrict__ psum,
                           const float* __restrict__ ptv, const int* __restrict__ pti,
                           const float* __restrict__ hdec, const float* __restrict__ wout,
                           const float* __restrict__ bout,
                           float* __restrict__ out, int* __restrict__ prev, int tstep)
{
    __shared__ float sv[256]; __shared__ int sti[256]; __shared__ int ssl[256];
    __shared__ float cvv[1000]; __shared__ int cii[1000];
    __shared__ float c8v[8]; __shared__ int c8i[8]; __shared__ float c8e[8];
    const int b = blockIdx.x, tid = threadIdx.x;
    const float* pm = pmax + (size_t)b * 500;
    const float* ps = psum + (size_t)b * 500;

    float m = -3.4e38f;
    for (int i = tid; i < 500; i += 256) m = fmaxf(m, pm[i]);
    sv[tid] = m; __syncthreads();
    for (int off = 128; off; off >>= 1) { if (tid < off) sv[tid] = fmaxf(sv[tid], sv[tid + off]); __syncthreads(); }
    float gmax = sv[0]; __syncthreads();

    float s = 0.f;
    for (int i = tid; i < 500; i += 256) s += ps[i] * expf(pm[i] - gmax);
    sv[tid] = s; __syncthreads();
    for (int off = 128; off; off >>= 1) { if (tid < off) sv[tid] += sv[tid + off]; __syncthreads(); }
    float gsum = sv[0]; __syncthreads();

    for (int i = tid; i < 1000; i += 256) { cvv[i] = ptv[(size_t)b * 1000 + i]; cii[i] = pti[(size_t)b * 1000 + i]; }
    __syncthreads();

    for (int c = 0; c < 8; ++c) {
        float bv = -3.4e38f; int bi = 0x7fffffff, bs = 0;
        for (int i = tid; i < 1000; i += 256) {
            float v = cvv[i]; int ix = cii[i];
            if (v > bv || (v == bv && ix < bi)) { bv = v; bi = ix; bs = i; }
        }
        sv[tid] = bv; sti[tid] = bi; ssl[tid] = bs; __syncthreads();
        for (int off = 128; off; off >>= 1) {
            if (tid < off) {
                if (sv[tid + off] > sv[tid] ||
                    (sv[tid + off] == sv[tid] && sti[tid + off] < sti[tid])) {
                    sv[tid] = sv[tid + off]; sti[tid] = sti[tid + off]; ssl[tid] = ssl[tid + off];
                }
            }
            __syncthreads();
        }
        if (tid == 0) { c8v[c] = sv[0]; c8i[c] = sti[0]; cvv[ssl[0]] = -3.4e38f; }
        __syncthreads();
    }

    {   // exact fp32 rescore, 2 candidates per wave
        int lane = tid & 63, wv = tid >> 6;
        const float* hr = hdec + (size_t)b * HID_;
        for (int c = wv; c < 8; c += 4) {
            const float* wr = wout + (size_t)c8i[c] * HID_;
            float a = 0.f;
            for (int k = lane * 4; k < HID_; k += 256) {
                float4 x = ld4(hr + k), y = ld4(wr + k);
                a += x.x * y.x + x.y * y.y + x.z * y.z + x.w * y.w;
            }
#pragma unroll
            for (int off = 32; off; off >>= 1) a += __shfl_down(a, off);
            if (lane == 0) c8e[c] = a + bout[c8i[c]];
        }
    }
    __syncthreads();

    if (tid == 0) {
        float bv = c8e[0]; int bi = c8i[0]; float av = c8v[0];
        for (int c = 1; c < 8; ++c)
            if (c8e[c] > bv || (c8e[c] == bv && c8i[c] < bi)) { bv = c8e[c]; bi = c8i[c]; av = c8v[c]; }
        float p = expf(av - gmax) / gsum;
        float lp = logf(p + 1e-12f);
        out[(size_t)b * TMAX_ + tstep] = (float)bi;
        out[B_ * TMAX_ + (size_t)b * TMAX_ + tstep] = lp;
        prev[b] = bi;
    }
}

// ---------------------------------------------------------------------------
extern "C" void kernel_launch(void* const* d_in, const int* in_sizes, int n_in,
                              void* d_out, int out_size, void* d_ws, size_t ws_size,
                              hipStream_t stream)
{
    const int*   ids   = (const int*)  d_in[0];
    const float* cvec  = (const float*)d_in[1];
    const float* emb   = (const float*)d_in[2];
    const float* wih_f = (const float*)d_in[3];
    const float* whh_f = (const float*)d_in[4];
    const float* bih_f = (const float*)d_in[5];
    const float* bhh_f = (const float*)d_in[6];
    const float* wih_b = (const float*)d_in[7];
    const float* whh_b = (const float*)d_in[8];
    const float* bih_b = (const float*)d_in[9];
    const float* bhh_b = (const float*)d_in[10];
    const float* dwih  = (const float*)d_in[11];
    const float* dwhh  = (const float*)d_in[12];
    const float* dbih  = (const float*)d_in[13];
    const float* dbhh  = (const float*)d_in[14];
    const float* wout  = (const float*)d_in[15];
    const float* bout  = (const float*)d_in[16];
    float* out = (float*)d_out;

    // workspace carve (floats); persistent total = 15,859,968 f = 63.4 MB
    float* w      = (float*)d_ws;
    float* gxc_f  = w;                          // 6,291,456  (16 steps x 256 x 1536)
    float* gxc_b  = w + 6291456;                // 6,291,456
    float* hT     = w + 12582912;               // 262,144  [dir][row][unit]
    float* hcat   = w + 12845056;               // 262,144
    float* hdec   = w + 13107200;               // 262,144
    float* gctx   = w + 13369344;               // 786,432
    u16*   hdecb  = (u16*)(w + 14155776);       // 131,072 f
    int*   prev   = (int*)(w + 14286848);       // 256
    float* whhX_f = w + 14287104;               // 786,432
    float* whhX_b = w + 15073536;               // 786,432
    // --- decoder-phase aliases over gxc region (dead after encoder) ---
    float* gibuf  = gxc_f;                      // 786,432
    float* ghbuf  = gxc_f + 786432;             // 786,432
    float* pmax   = gxc_f + 1572864;            // 128,000
    float* psum   = gxc_f + 1700864;            // 128,000
    float* ptv    = gxc_f + 1828864;            // 256,000
    int*   pti    = (int*)(gxc_f + 2084864);    // 256,000

    zerof<<<1024, 256, 0, stream>>>(hT, 262144);
    init_dec<<<1024, 256, 0, stream>>>(hdec, hdecb, prev);
    whh_trans<<<dim3(3072, 2), 256, 0, stream>>>(whh_f, whh_b, whhX_f, whhX_b);

    // ---------------- encoder: 8 chunks x 16 steps, no grid syncs ----------------
    for (int c = 0; c < 8; ++c) {
        enc_gx2<<<dim3(12, 32, 2), 256, 0, stream>>>(
            wih_f, wih_b, bih_f, bih_b, ids, emb, gxc_f, gxc_b, c);
        enc_rec<<<128, 512, 0, stream>>>(
            gxc_f, gxc_b, whhX_f, whhX_b, bhh_f, bhh_b, hT, 16);
    }

    hcat_build<<<1024, 256, 0, stream>>>(hT, hcat);

    // gctx[b][3072] = [hcat|cvec] @ dec_wih[:,512:1600]^T + dbih
    gemm_nt<64, 64, 4, 4, 2, 0, 0><<<dim3(48, 4), 256, 0, stream>>>(
        hcat, nullptr, cvec, dwih, 1600, 512, dbih, nullptr,
        gctx, 3072, 1024, 1088, 0, 0);

    // ---------------- decoder: 40 greedy steps ----------------
    for (int t = 0; t < TMAX_; ++t) {
        dec_gemm2<<<dim3(48, 8), 256, 0, stream>>>(
            hdec, prev, emb, dwhh, dwih, dbhh, gctx, ghbuf, gibuf);
        dec_combine<<<1024, 256, 0, stream>>>(gibuf, ghbuf, hdec, hdecb);
        gemm_logits<<<dim3(250, 1), 512, 0, stream>>>(hdecb, wout, bout,
                                                      pmax, psum, ptv, pti);
        dec_reduce<<<256, 256, 0, stream>>>(pmax, psum, ptv, pti,
                                            hdec, wout, bout, out, prev, t);
    }
}

// Round 3
// 10646.440 us; speedup vs baseline: 1.6943x; 1.0762x over previous
//
#include <hip/hip_runtime.h>
#include <hip/hip_bf16.h>
#include <math.h>

#define B_    256
#define S_    128
#define EMB_  512
#define H2_   512
#define HID_  1024
#define CTX_  64
#define VOC_  32000
#define TMAX_ 40
#define SOS_  2

typedef unsigned short u16;
typedef __attribute__((ext_vector_type(8))) short short8;
typedef __attribute__((ext_vector_type(4))) float f32x4;

__device__ __forceinline__ float4 ld4(const float* p) {
    return *reinterpret_cast<const float4*>(p);
}
__device__ __forceinline__ float sigmoidf_(float x) { return 1.f / (1.f + expf(-x)); }
__device__ __forceinline__ u16 f2bf(float x) {
    union { float f; unsigned int u; } v; v.f = x;
    unsigned int r = v.u + 0x7FFFu + ((v.u >> 16) & 1u);
    return (u16)(r >> 16);
}
__device__ __forceinline__ unsigned pk2(float a, float b) {
    float2 t; t.x = a; t.y = b;
    __hip_bfloat162 h = __float22bfloat162_rn(t);
    return *reinterpret_cast<unsigned*>(&h);
}
// merge two (value desc, index asc)-ordered top-2 pairs
__device__ __forceinline__ void merge_top2(float& v1, int& i1, float& v2, int& i2,
                                           float ov1, int oi1, float ov2, int oi2)
{
    if (ov1 > v1 || (ov1 == v1 && oi1 < i1)) {
        float tv = v1; int ti = i1;
        v1 = ov1; i1 = oi1;
        if (ov2 > tv || (ov2 == tv && oi2 < ti)) { v2 = ov2; i2 = oi2; }
        else                                     { v2 = tv;  i2 = ti;  }
    } else {
        if (ov1 > v2 || (ov1 == v2 && oi1 < i2)) { v2 = ov1; i2 = oi1; }
    }
}

// ---------------------------------------------------------------------------
// fp32 tiled GEMM (kept for the one-shot gctx GEMM):
// C[m][n] = sum_k A[m][k]*B[n][k] (+bias) (+addsrc)
// ---------------------------------------------------------------------------
template<int BM, int BN, int TM, int TN, int AMODE, int BGATHER, int BIASM>
__launch_bounds__(256)
__global__ void gemm_nt(const float* __restrict__ Ap,
                        const int*   __restrict__ ids,
                        const float* __restrict__ Ex,
                        const float* __restrict__ Bp, int ldb, int bofs,
                        const float* __restrict__ bias,
                        const float* __restrict__ addsrc,
                        float* __restrict__ Cp, int ldc,
                        int lda, int K, int s_base, int sdir)
{
    constexpr int BK = 32;
    __shared__ float As[BK][BM + 4];
    __shared__ float Bs[BK][BN + 4];
    const int t  = threadIdx.x;
    const int tx = t & 15, ty = t >> 4;
    const int m_base = blockIdx.y * BM;
    const int n_base = blockIdx.x * BN;

    float acc[TM][TN];
#pragma unroll
    for (int i = 0; i < TM; ++i)
#pragma unroll
        for (int j = 0; j < TN; ++j) acc[i][j] = 0.f;

    constexpr int A_PER = BM * BK / 4 / 256;
    constexpr int B_PER = BN * BK / 4 / 256;

    for (int k0 = 0; k0 < K; k0 += BK) {
#pragma unroll
        for (int j = 0; j < A_PER; ++j) {
            int f   = t + j * 256;
            int row = f >> 3;
            int kk  = (f & 7) << 2;
            int m   = m_base + row;
            float4 v;
            if constexpr (AMODE == 0) {
                v = ld4(Ap + (size_t)m * lda + k0 + kk);
            } else if constexpr (AMODE == 3) {
                int id = ids[m];
                v = ld4(Ex + (size_t)id * EMB_ + k0 + kk);
            } else {  // AMODE == 2
                int k = k0 + kk;
                if (k < HID_) v = ld4(Ap + (size_t)m * HID_ + k);
                else          v = ld4(Ex + (size_t)m * CTX_ + (k - HID_));
            }
            As[kk + 0][row] = v.x; As[kk + 1][row] = v.y;
            As[kk + 2][row] = v.z; As[kk + 3][row] = v.w;
        }
#pragma unroll
        for (int j = 0; j < B_PER; ++j) {
            int f   = t + j * 256;
            int row = f >> 3;
            int kk  = (f & 7) << 2;
            float4 v;
            if constexpr (BGATHER == 1) {
                int n = n_base + row;
                int s = n >> 8, b = n & 255;
                int id = ids[b * S_ + s_base + sdir * s];
                v = ld4(Ex + (size_t)id * EMB_ + k0 + kk);
            } else {
                v = ld4(Bp + (size_t)(n_base + row) * ldb + bofs + k0 + kk);
            }
            Bs[kk + 0][row] = v.x; Bs[kk + 1][row] = v.y;
            Bs[kk + 2][row] = v.z; Bs[kk + 3][row] = v.w;
        }
        __syncthreads();
#pragma unroll
        for (int kk = 0; kk < BK; ++kk) {
            float a[TM], b[TN];
            *(float4*)&a[0] = ld4(&As[kk][ty * TM]);
            if constexpr (TM == 8) *(float4*)&a[4] = ld4(&As[kk][ty * TM + 4]);
            *(float4*)&b[0] = ld4(&Bs[kk][tx * TN]);
            if constexpr (TN == 8) *(float4*)&b[4] = ld4(&Bs[kk][tx * TN + 4]);
#pragma unroll
            for (int i = 0; i < TM; ++i)
#pragma unroll
                for (int j = 0; j < TN; ++j) acc[i][j] += a[i] * b[j];
        }
        __syncthreads();
    }
#pragma unroll
    for (int i = 0; i < TM; ++i) {
        int m = m_base + ty * TM + i;
#pragma unroll
        for (int j = 0; j < TN; ++j) {
            int n = n_base + tx * TN + j;
            float v = acc[i][j];
            if (bias) v += BIASM ? bias[m] : bias[n];
            if (addsrc) v += addsrc[(size_t)m * ldc + n];
            Cp[(size_t)m * ldc + n] = v;
        }
    }
}

// ---------------------------------------------------------------------------
// whh transpose/interleave: whhX[k][u*3+g] = whh[g*512+u][k].  One-time.
// ---------------------------------------------------------------------------
__global__ void whh_trans(const float* __restrict__ whh_f, const float* __restrict__ whh_b,
                          float* __restrict__ whhX_f, float* __restrict__ whhX_b)
{
    int idx = blockIdx.x * 256 + threadIdx.x;        // [0, 786432)
    const float* src = blockIdx.y ? whh_b : whh_f;
    float*       dst = blockIdx.y ? whhX_b : whhX_f;
    int k  = idx / 1536;
    int cc = idx - k * 1536;
    int u  = cc / 3;
    int g  = cc - u * 3;
    dst[idx] = src[(size_t)(g * 512 + u) * 512 + k];
}

// ---------------------------------------------------------------------------
// Fused encoder super-kernel: 512 blocks x 512 threads.
//   blocks [0,128)   : GRU recurrence for current chunk (8 steps, batch-par,
//                      no grid sync; h in LDS; whhX streamed from XCD-L2).
//   blocks [128,512) : gx GEMM for NEXT chunk into the other double buffer:
//                      gx[s*256+b][col] = emb[ids] @ wih^T + bih  (M=2048,
//                      N=1536, K=512, both dirs: 2x192 tiles of 128x128).
// The two paths are data-independent within a dispatch (rec reads buf A,
// gx writes buf B); stream order provides the cross-dispatch dependency.
// Heterogeneous co-residency: gx waves fill the VALU slots rec's L2-latency
// stalls leave idle.
// ---------------------------------------------------------------------------
#define RECBLK 128

union EncSM {
    struct { float hbuf[2][512][4]; float red[256][25]; } rec;   // 16K + 25.6K
    struct { float As[32][132]; float Bs[32][132]; } gx;         // 33.8K
};

__launch_bounds__(512)
__global__ void enc_fused(const float* __restrict__ grec_f, const float* __restrict__ grec_b,
                          float* __restrict__ gout_f, float* __restrict__ gout_b,
                          const float* __restrict__ whhX_f, const float* __restrict__ whhX_b,
                          const float* __restrict__ bhh_f, const float* __restrict__ bhh_b,
                          const float* __restrict__ wih_f, const float* __restrict__ wih_b,
                          const float* __restrict__ bih_f, const float* __restrict__ bih_b,
                          const int* __restrict__ ids, const float* __restrict__ emb,
                          float* __restrict__ hT, int do_rec, int gx_chunk, int nsteps)
{
    __shared__ __align__(16) EncSM sm;
    const int t = threadIdx.x;

    if (blockIdx.x >= RECBLK) {
        // ---------------- gx GEMM path ----------------
        if (gx_chunk < 0) return;
        const int tt  = blockIdx.x - RECBLK;          // [0,384)
        const int dz  = tt >= 192;
        const int t192 = dz ? tt - 192 : tt;
        const int m_base = (t192 & 15) * 128;         // M = 2048
        const int n_base = (t192 >> 4) * 128;         // N = 1536
        const float* W    = dz ? wih_b : wih_f;
        const float* bias = dz ? bih_b : bih_f;
        float*       Cp   = dz ? gout_b : gout_f;
        const int s_base  = dz ? (127 - 8 * gx_chunk) : (8 * gx_chunk);
        const int sdir    = dz ? -1 : 1;
        const int tx = t & 31, ty = t >> 5;           // 32 x 16

        float acc[8][4];
#pragma unroll
        for (int i = 0; i < 8; ++i)
#pragma unroll
            for (int j = 0; j < 4; ++j) acc[i][j] = 0.f;

        for (int k0 = 0; k0 < 512; k0 += 32) {
#pragma unroll
            for (int j = 0; j < 2; ++j) {
                int f   = t + j * 512;
                int row = f >> 3;
                int kk  = (f & 7) << 2;
                int m   = m_base + row;
                int s   = m >> 8, b = m & 255;
                int id  = ids[b * S_ + s_base + sdir * s];
                float4 v = ld4(emb + (size_t)id * EMB_ + k0 + kk);
                sm.gx.As[kk + 0][row] = v.x; sm.gx.As[kk + 1][row] = v.y;
                sm.gx.As[kk + 2][row] = v.z; sm.gx.As[kk + 3][row] = v.w;
                float4 wv = ld4(W + (size_t)(n_base + row) * 512 + k0 + kk);
                sm.gx.Bs[kk + 0][row] = wv.x; sm.gx.Bs[kk + 1][row] = wv.y;
                sm.gx.Bs[kk + 2][row] = wv.z; sm.gx.Bs[kk + 3][row] = wv.w;
            }
            __syncthreads();
#pragma unroll
            for (int kk = 0; kk < 32; ++kk) {
                float a[8], b[4];
                *(float4*)&a[0] = ld4(&sm.gx.As[kk][ty * 8]);
                *(float4*)&a[4] = ld4(&sm.gx.As[kk][ty * 8 + 4]);
                *(float4*)&b[0] = ld4(&sm.gx.Bs[kk][tx * 4]);
#pragma unroll
                for (int i = 0; i < 8; ++i)
#pragma unroll
                    for (int j = 0; j < 4; ++j) acc[i][j] += a[i] * b[j];
            }
            __syncthreads();
        }
#pragma unroll
        for (int i = 0; i < 8; ++i) {
            int m = m_base + ty * 8 + i;
#pragma unroll
            for (int j = 0; j < 4; ++j) {
                int n = n_base + tx * 4 + j;
                Cp[(size_t)m * 1536 + n] = acc[i][j] + bias[n];
            }
        }
        return;
    }

    // ---------------- recurrence path ----------------
    if (!do_rec) return;
    const int bid = blockIdx.x;
    const int xcd = bid & 7;
    const int dir = xcd >> 2;
    const int local = (bid >> 3) * 4 + (xcd & 3);     // [0,64)
    const int r0 = local * 4;
    const float* gx  = dir ? grec_b : grec_f;
    const float* whx = dir ? whhX_b : whhX_f;
    const float* bhh = dir ? bhh_b : bhh_f;
    float* hTd = hT + (size_t)dir * (256 * 512);

    const int kh = t >> 8;          // k half: 0 -> k in [0,256), 1 -> [256,512)
    const int tu = t & 255;         // unit pair: units 2tu, 2tu+1
    const int k_base = kh << 8;

    for (int i = t; i < 2048; i += 512) {
        int r = i >> 9, u = i & 511;
        sm.rec.hbuf[0][u][r] = hTd[(size_t)(r0 + r) * 512 + u];
    }
    float bh[2][3];
#pragma unroll
    for (int uu = 0; uu < 2; ++uu)
#pragma unroll
        for (int g = 0; g < 3; ++g)
            bh[uu][g] = bhh[g * 512 + tu * 2 + uu];
    __syncthreads();

    for (int st = 0; st < nsteps; ++st) {
        const int cur = st & 1, nxt = cur ^ 1;

        // issue gx gate loads EARLY so L2/HBM latency hides under the k-loop
        float2 gxv[3][4];
        if (!kh) {
#pragma unroll
            for (int g = 0; g < 3; ++g)
#pragma unroll
                for (int r = 0; r < 4; ++r)
                    gxv[g][r] = *(const float2*)&gx[(size_t)((st << 8) + r0 + r) * 1536
                                                    + (g << 9) + (tu << 1)];
        }

        float acc[2][3][4];
#pragma unroll
        for (int uu = 0; uu < 2; ++uu)
#pragma unroll
            for (int g = 0; g < 3; ++g)
#pragma unroll
                for (int r = 0; r < 4; ++r) acc[uu][g][r] = 0.f;

        const float* wp = whx + (size_t)k_base * 1536 + tu * 6;
#pragma unroll 4
        for (int kk = 0; kk < 256; ++kk) {
            float4 hv = *(const float4*)&sm.rec.hbuf[cur][k_base + kk][0];
            float2 w0 = *(const float2*)(wp + 0);   // (u0,r) (u0,z)
            float2 w1 = *(const float2*)(wp + 2);   // (u0,n) (u1,r)
            float2 w2 = *(const float2*)(wp + 4);   // (u1,z) (u1,n)
            const float* hvp = (const float*)&hv;
#pragma unroll
            for (int r = 0; r < 4; ++r) {
                float h = hvp[r];
                acc[0][0][r] += w0.x * h;
                acc[0][1][r] += w0.y * h;
                acc[0][2][r] += w1.x * h;
                acc[1][0][r] += w1.y * h;
                acc[1][1][r] += w2.x * h;
                acc[1][2][r] += w2.y * h;
            }
            wp += 1536;
        }

        if (kh) {
#pragma unroll
            for (int uu = 0; uu < 2; ++uu)
#pragma unroll
                for (int g = 0; g < 3; ++g)
#pragma unroll
                    for (int r = 0; r < 4; ++r)
                        sm.rec.red[tu][(uu * 3 + g) * 4 + r] = acc[uu][g][r];
        }
        __syncthreads();
        if (!kh) {
#pragma unroll
            for (int uu = 0; uu < 2; ++uu)
#pragma unroll
                for (int g = 0; g < 3; ++g)
#pragma unroll
                    for (int r = 0; r < 4; ++r)
                        acc[uu][g][r] += sm.rec.red[tu][(uu * 3 + g) * 4 + r];
#pragma unroll
            for (int uu = 0; uu < 2; ++uu) {
                int u = tu * 2 + uu;
#pragma unroll
                for (int r = 0; r < 4; ++r) {
                    float gr = uu ? gxv[0][r].y : gxv[0][r].x;
                    float gz = uu ? gxv[1][r].y : gxv[1][r].x;
                    float gn = uu ? gxv[2][r].y : gxv[2][r].x;
                    float hold = sm.rec.hbuf[cur][u][r];
                    float rg = sigmoidf_(gr + acc[uu][0][r] + bh[uu][0]);
                    float zg = sigmoidf_(gz + acc[uu][1][r] + bh[uu][1]);
                    float ng = tanhf(gn + rg * (acc[uu][2][r] + bh[uu][2]));
                    sm.rec.hbuf[nxt][u][r] = (1.f - zg) * ng + zg * hold;
                }
            }
        }
        __syncthreads();
    }

    const int lb = nsteps & 1;
    for (int i = t; i < 2048; i += 512) {
        int r = i >> 9, u = i & 511;
        hTd[(size_t)(r0 + r) * 512 + u] = sm.rec.hbuf[lb][u][r];
    }
}

// ---------------------------------------------------------------------------
__global__ void zerof(float* __restrict__ p, int n)
{
    int i = blockIdx.x * 256 + threadIdx.x;
    if (i < n) p[i] = 0.f;
}

__global__ void init_dec(float* __restrict__ hdec, u16* __restrict__ hbf, int* __restrict__ prev)
{
    int i = blockIdx.x * 256 + threadIdx.x;   // 262144
    hdec[i] = 0.f; hbf[i] = 0;
    if (i < B_) prev[i] = SOS_;
}

// hcat (torch h_n.view quirk): hcat[b][k] = h_dir(b>>7)[(2b)&255 + (k>>9)][k&511]
// hT layout: [dir][row 256][unit 512]
__global__ void hcat_build(const float* __restrict__ hT, float* __restrict__ hcat)
{
    int idx = blockIdx.x * 256 + threadIdx.x; // 262144
    int b = idx >> 10, k = idx & 1023;
    int d = b >> 7;
    int rr = ((2 * b) & 255) + (k >> 9);
    int kk = k & 511;
    hcat[idx] = hT[(size_t)d * 131072 + (size_t)rr * 512 + kk];
}

// ---------------------------------------------------------------------------
// Decoder gh + gi GEMMs fused into ONE launch.  grid (48, 8): blockIdx.y<4 ->
// gh (A=hdec, K=1024, B=dwhh, +dbhh[n]); else -> gi (A=emb[prev], K=512,
// B=dwih[:, :512], +gctx).  64x64 tile, 4x4 per thread, BK=32.
// ---------------------------------------------------------------------------
__launch_bounds__(256)
__global__ void dec_gemm2(const float* __restrict__ hdec, const int* __restrict__ prev,
                          const float* __restrict__ emb,
                          const float* __restrict__ dwhh, const float* __restrict__ dwih,
                          const float* __restrict__ dbhh, const float* __restrict__ gctx,
                          float* __restrict__ ghbuf, float* __restrict__ gibuf)
{
    constexpr int BK = 32;
    __shared__ float As[BK][68];
    __shared__ float Bs[BK][68];
    const int t  = threadIdx.x;
    const int tx = t & 15, ty = t >> 4;
    const bool isH = blockIdx.y < 4;
    const int m_base = (isH ? blockIdx.y : (blockIdx.y - 4)) * 64;
    const int n_base = blockIdx.x * 64;
    const int K   = isH ? 1024 : 512;
    const float* Bp = isH ? dwhh : dwih;
    const int ldb  = isH ? 1024 : 1600;
    float* Cp = isH ? ghbuf : gibuf;

    float acc[4][4];
#pragma unroll
    for (int i = 0; i < 4; ++i)
#pragma unroll
        for (int j = 0; j < 4; ++j) acc[i][j] = 0.f;

    for (int k0 = 0; k0 < K; k0 += BK) {
#pragma unroll
        for (int j = 0; j < 2; ++j) {
            int f   = t + j * 256;
            int row = f >> 3;
            int kk  = (f & 7) << 2;
            int m   = m_base + row;
            float4 v;
            if (isH) v = ld4(hdec + (size_t)m * HID_ + k0 + kk);
            else     v = ld4(emb + (size_t)prev[m] * EMB_ + k0 + kk);
            As[kk + 0][row] = v.x; As[kk + 1][row] = v.y;
            As[kk + 2][row] = v.z; As[kk + 3][row] = v.w;
            float4 w = ld4(Bp + (size_t)(n_base + row) * ldb + k0 + kk);
            Bs[kk + 0][row] = w.x; Bs[kk + 1][row] = w.y;
            Bs[kk + 2][row] = w.z; Bs[kk + 3][row] = w.w;
        }
        __syncthreads();
#pragma unroll
        for (int kk = 0; kk < BK; ++kk) {
            float a[4], b[4];
            *(float4*)&a[0] = ld4(&As[kk][ty * 4]);
            *(float4*)&b[0] = ld4(&Bs[kk][tx * 4]);
#pragma unroll
            for (int i = 0; i < 4; ++i)
#pragma unroll
                for (int j = 0; j < 4; ++j) acc[i][j] += a[i] * b[j];
        }
        __syncthreads();
    }
#pragma unroll
    for (int i = 0; i < 4; ++i) {
        int m = m_base + ty * 4 + i;
#pragma unroll
        for (int j = 0; j < 4; ++j) {
            int n = n_base + tx * 4 + j;
            float v = acc[i][j];
            if (isH) v += dbhh[n];
            else     v += gctx[(size_t)m * 3072 + n];
            Cp[(size_t)m * 3072 + n] = v;
        }
    }
}

__global__ void dec_combine(const float* __restrict__ gi, const float* __restrict__ gh,
                            float* __restrict__ hdec, u16* __restrict__ hbf)
{
    int idx = blockIdx.x * 256 + threadIdx.x;  // 262144
    int b = idx >> 10, u = idx & 1023;
    size_t gb = (size_t)b * 3072;
    float r = sigmoidf_(gi[gb + u]            + gh[gb + u]);
    float z = sigmoidf_(gi[gb + HID_ + u]     + gh[gb + HID_ + u]);
    float n = tanhf    (gi[gb + 2 * HID_ + u] + r * gh[gb + 2 * HID_ + u]);
    float v = (1.f - z) * n + z * hdec[idx];
    hdec[idx] = v;
    hbf[idx] = f2bf(v);
}

// ---------------------------------------------------------------------------
// Fused bf16 MFMA logits + per-row softmax/top2 partials. No logits buffer.
// Single m-pass: BM=256 (all rows), BN=128, 512 threads = 8 waves (4m x 2n).
// Per row x 64-col half: (max, sumexp, top2 val/idx) partials, 500/row.
// ---------------------------------------------------------------------------
__launch_bounds__(512)
__global__ void gemm_logits(const u16* __restrict__ A, const float* __restrict__ Wf,
                            const float* __restrict__ bias,
                            float* __restrict__ pmax, float* __restrict__ psum,
                            float* __restrict__ ptv, int* __restrict__ pti)
{
    __shared__ u16 As[256][72];
    __shared__ u16 Bs[128][72];
    const int t = threadIdx.x;
    const int lane = t & 63, wave = t >> 6;
    const int wm = (wave & 3) * 64, wn = (wave >> 2) * 64;
    const int n0 = blockIdx.x * 128;
    f32x4 acc[4][4];
#pragma unroll
    for (int i = 0; i < 4; ++i)
#pragma unroll
        for (int j = 0; j < 4; ++j) acc[i][j] = (f32x4){0.f, 0.f, 0.f, 0.f};
    const int arow = t >> 1, aoff = (t & 1) * 32;
    const int brow = t >> 2, boff = (t & 3) * 16;

    for (int k0 = 0; k0 < 1024; k0 += 64) {
#pragma unroll
        for (int q = 0; q < 4; ++q) {
            *(uint4*)&As[arow][aoff + q * 8] =
                *(const uint4*)(A + (size_t)arow * 1024 + k0 + aoff + q * 8);
        }
        const float* wr = Wf + (size_t)(n0 + brow) * 1024 + k0 + boff;
#pragma unroll
        for (int q = 0; q < 2; ++q) {
            float4 x = ld4(wr + q * 8);
            float4 y = ld4(wr + q * 8 + 4);
            uint4 o;
            o.x = pk2(x.x, x.y); o.y = pk2(x.z, x.w);
            o.z = pk2(y.x, y.y); o.w = pk2(y.z, y.w);
            *(uint4*)&Bs[brow][boff + q * 8] = o;
        }
        __syncthreads();
#pragma unroll
        for (int s = 0; s < 2; ++s) {
            short8 a[4], b[4];
            int j0 = s * 32 + (lane >> 4) * 8;
#pragma unroll
            for (int i = 0; i < 4; ++i) {
                a[i] = *(const short8*)&As[wm + i * 16 + (lane & 15)][j0];
                b[i] = *(const short8*)&Bs[wn + i * 16 + (lane & 15)][j0];
            }
#pragma unroll
            for (int i = 0; i < 4; ++i)
#pragma unroll
                for (int j = 0; j < 4; ++j)
                    acc[i][j] = __builtin_amdgcn_mfma_f32_16x16x32_bf16(a[i], b[j], acc[i][j], 0, 0, 0);
        }
        __syncthreads();
    }

    // ---- fused epilogue: per-row (max, sumexp, top2) over this wave's 64 cols
    const int htile = blockIdx.x * 2 + (wn >> 6);
    float bn[4]; int jx[4];
#pragma unroll
    for (int j = 0; j < 4; ++j) { jx[j] = n0 + wn + j * 16 + (lane & 15); bn[j] = bias[jx[j]]; }
#pragma unroll
    for (int i = 0; i < 4; ++i) {
#pragma unroll
        for (int rr = 0; rr < 4; ++rr) {
            float v[4];
#pragma unroll
            for (int j = 0; j < 4; ++j) v[j] = acc[i][j][rr] + bn[j];
            float v1 = v[0], v2 = -3.4e38f; int i1 = jx[0], i2 = 0x7fffffff;
#pragma unroll
            for (int j = 1; j < 4; ++j) {
                if (v[j] > v1)      { v2 = v1; i2 = i1; v1 = v[j]; i1 = jx[j]; }
                else if (v[j] > v2) { v2 = v[j]; i2 = jx[j]; }
            }
#pragma unroll
            for (int mask = 1; mask <= 8; mask <<= 1) {
                float ov1 = __shfl_xor(v1, mask), ov2 = __shfl_xor(v2, mask);
                int   oi1 = __shfl_xor(i1, mask), oi2 = __shfl_xor(i2, mask);
                merge_top2(v1, i1, v2, i2, ov1, oi1, ov2, oi2);
            }
            float rmax = v1;
            float s = 0.f;
#pragma unroll
            for (int j = 0; j < 4; ++j) s += expf(v[j] - rmax);
#pragma unroll
            for (int mask = 1; mask <= 8; mask <<= 1) s += __shfl_xor(s, mask);
            if ((lane & 15) == 0) {
                int row = wm + i * 16 + (lane >> 4) * 4 + rr;
                size_t base = (size_t)row * 500 + htile;
                pmax[base] = rmax; psum[base] = s;
                ptv[base * 2] = v1; ptv[base * 2 + 1] = v2;
                pti[base * 2] = i1; pti[base * 2 + 1] = i2;
            }
        }
    }
}

// ---------------------------------------------------------------------------
// Per-row combine of 500 half-tile partials: global max/sumexp, top-8 from
// 1000 candidates, exact fp32 rescore (first-index tie-break), token + lp.
// ---------------------------------------------------------------------------
__launch_bounds__(256)
__global__ void dec_reduce(const float* __restrict__ pmax, const float* __restrict__ psum,
                           const float* __restrict__ ptv, const int* __restrict__ pti,
                           const float* __restrict__ hdec, const float* __restrict__ wout,
                           const float* __restrict__ bout,
                           float* __restrict__ out, int* __restrict__ prev, int tstep)
{
    __shared__ float sv[256]; __shared__ int sti[256]; __shared__ int ssl[256];
    __shared__ float cvv[1000]; __shared__ int cii[1000];
    __shared__ float c8v[8]; __shared__ int c8i[8]; __shared__ float c8e[8];
    const int b = blockIdx.x, tid = threadIdx.x;
    const float* pm = pmax + (size_t)b * 500;
    const float* ps = psum + (size_t)b * 500;

    float m = -3.4e38f;
    for (int i = tid; i < 500; i += 256) m = fmaxf(m, pm[i]);
    sv[tid] = m; __syncthreads();
    for (int off = 128; off; off >>= 1) { if (tid < off) sv[tid] = fmaxf(sv[tid], sv[tid + off]); __syncthreads(); }
    float gmax = sv[0]; __syncthreads();

    float s = 0.f;
    for (int i = tid; i < 500; i += 256) s += ps[i] * expf(pm[i] - gmax);
    sv[tid] = s; __syncthreads();
    for (int off = 128; off; off >>= 1) { if (tid < off) sv[tid] += sv[tid + off]; __syncthreads(); }
    float gsum = sv[0]; __syncthreads();

    for (int i = tid; i < 1000; i += 256) { cvv[i] = ptv[(size_t)b * 1000 + i]; cii[i] = pti[(size_t)b * 1000 + i]; }
    __syncthreads();

    for (int c = 0; c < 8; ++c) {
        float bv = -3.4e38f; int bi = 0x7fffffff, bs = 0;
        for (int i = tid; i < 1000; i += 256) {
            float v = cvv[i]; int ix = cii[i];
            if (v > bv || (v == bv && ix < bi)) { bv = v; bi = ix; bs = i; }
        }
        sv[tid] = bv; sti[tid] = bi; ssl[tid] = bs; __syncthreads();
        for (int off = 128; off; off >>= 1) {
            if (tid < off) {
                if (sv[tid + off] > sv[tid] ||
                    (sv[tid + off] == sv[tid] && sti[tid + off] < sti[tid])) {
                    sv[tid] = sv[tid + off]; sti[tid] = sti[tid + off]; ssl[tid] = ssl[tid + off];
                }
            }
            __syncthreads();
        }
        if (tid == 0) { c8v[c] = sv[0]; c8i[c] = sti[0]; cvv[ssl[0]] = -3.4e38f; }
        __syncthreads();
    }

    {   // exact fp32 rescore, 2 candidates per wave
        int lane = tid & 63, wv = tid >> 6;
        const float* hr = hdec + (size_t)b * HID_;
        for (int c = wv; c < 8; c += 4) {
            const float* wr = wout + (size_t)c8i[c] * HID_;
            float a = 0.f;
            for (int k = lane * 4; k < HID_; k += 256) {
                float4 x = ld4(hr + k), y = ld4(wr + k);
                a += x.x * y.x + x.y * y.y + x.z * y.z + x.w * y.w;
            }
#pragma unroll
            for (int off = 32; off; off >>= 1) a += __shfl_down(a, off);
            if (lane == 0) c8e[c] = a + bout[c8i[c]];
        }
    }
    __syncthreads();

    if (tid == 0) {
        float bv = c8e[0]; int bi = c8i[0]; float av = c8v[0];
        for (int c = 1; c < 8; ++c)
            if (c8e[c] > bv || (c8e[c] == bv && c8i[c] < bi)) { bv = c8e[c]; bi = c8i[c]; av = c8v[c]; }
        float p = expf(av - gmax) / gsum;
        float lp = logf(p + 1e-12f);
        out[(size_t)b * TMAX_ + tstep] = (float)bi;
        out[B_ * TMAX_ + (size_t)b * TMAX_ + tstep] = lp;
        prev[b] = bi;
    }
}

// ---------------------------------------------------------------------------
extern "C" void kernel_launch(void* const* d_in, const int* in_sizes, int n_in,
                              void* d_out, int out_size, void* d_ws, size_t ws_size,
                              hipStream_t stream)
{
    const int*   ids   = (const int*)  d_in[0];
    const float* cvec  = (const float*)d_in[1];
    const float* emb   = (const float*)d_in[2];
    const float* wih_f = (const float*)d_in[3];
    const float* whh_f = (const float*)d_in[4];
    const float* bih_f = (const float*)d_in[5];
    const float* bhh_f = (const float*)d_in[6];
    const float* wih_b = (const float*)d_in[7];
    const float* whh_b = (const float*)d_in[8];
    const float* bih_b = (const float*)d_in[9];
    const float* bhh_b = (const float*)d_in[10];
    const float* dwih  = (const float*)d_in[11];
    const float* dwhh  = (const float*)d_in[12];
    const float* dbih  = (const float*)d_in[13];
    const float* dbhh  = (const float*)d_in[14];
    const float* wout  = (const float*)d_in[15];
    const float* bout  = (const float*)d_in[16];
    float* out = (float*)d_out;

    // workspace carve (floats); persistent total = 15,859,968 f = 63.4 MB
    // gx double buffer: [buf][dir], 8 steps x 256 x 1536 each.
    float* w      = (float*)d_ws;
    float* buf0_f = w;                          // 3,145,728
    float* buf0_b = w + 3145728;                // 3,145,728
    float* buf1_f = w + 6291456;                // 3,145,728
    float* buf1_b = w + 9437184;                // 3,145,728
    float* hT     = w + 12582912;               // 262,144  [dir][row][unit]
    float* hcat   = w + 12845056;               // 262,144
    float* hdec   = w + 13107200;               // 262,144
    float* gctx   = w + 13369344;               // 786,432
    u16*   hdecb  = (u16*)(w + 14155776);       // 131,072 f
    int*   prev   = (int*)(w + 14286848);       // 256
    float* whhX_f = w + 14287104;               // 786,432
    float* whhX_b = w + 15073536;               // 786,432
    // --- decoder-phase aliases over gx region (dead after encoder) ---
    float* gibuf  = buf0_f;                     // 786,432
    float* ghbuf  = buf0_f + 786432;            // 786,432
    float* pmax   = buf0_f + 1572864;           // 128,000
    float* psum   = buf0_f + 1700864;           // 128,000
    float* ptv    = buf0_f + 1828864;           // 256,000
    int*   pti    = (int*)(buf0_f + 2084864);   // 256,000

    zerof<<<1024, 256, 0, stream>>>(hT, 262144);
    init_dec<<<1024, 256, 0, stream>>>(hdec, hdecb, prev);
    whh_trans<<<dim3(3072, 2), 256, 0, stream>>>(whh_f, whh_b, whhX_f, whhX_b);

    // ---------------- encoder: 16 chunks x 8 steps, pipelined fused launches --------
    // dispatch 0: gx(chunk0) only; dispatches 1..15: rec(c-1) || gx(c);
    // dispatch 16: rec(15) only.
    enc_fused<<<512, 512, 0, stream>>>(
        buf0_f, buf0_b, buf0_f, buf0_b, whhX_f, whhX_b, bhh_f, bhh_b,
        wih_f, wih_b, bih_f, bih_b, ids, emb, hT, 0, 0, 8);
    for (int c = 1; c < 16; ++c) {
        float* rf = ((c - 1) & 1) ? buf1_f : buf0_f;
        float* rb = ((c - 1) & 1) ? buf1_b : buf0_b;
        float* of = (c & 1) ? buf1_f : buf0_f;
        float* ob = (c & 1) ? buf1_b : buf0_b;
        enc_fused<<<512, 512, 0, stream>>>(
            rf, rb, of, ob, whhX_f, whhX_b, bhh_f, bhh_b,
            wih_f, wih_b, bih_f, bih_b, ids, emb, hT, 1, c, 8);
    }
    enc_fused<<<512, 512, 0, stream>>>(
        buf1_f, buf1_b, buf1_f, buf1_b, whhX_f, whhX_b, bhh_f, bhh_b,
        wih_f, wih_b, bih_f, bih_b, ids, emb, hT, 1, -1, 8);

    hcat_build<<<1024, 256, 0, stream>>>(hT, hcat);

    // gctx[b][3072] = [hcat|cvec] @ dec_wih[:,512:1600]^T + dbih
    gemm_nt<64, 64, 4, 4, 2, 0, 0><<<dim3(48, 4), 256, 0, stream>>>(
        hcat, nullptr, cvec, dwih, 1600, 512, dbih, nullptr,
        gctx, 3072, 1024, 1088, 0, 0);

    // ---------------- decoder: 40 greedy steps ----------------
    for (int t = 0; t < TMAX_; ++t) {
        dec_gemm2<<<dim3(48, 8), 256, 0, stream>>>(
            hdec, prev, emb, dwhh, dwih, dbhh, gctx, ghbuf, gibuf);
        dec_combine<<<1024, 256, 0, stream>>>(gibuf, ghbuf, hdec, hdecb);
        gemm_logits<<<dim3(250, 1), 512, 0, stream>>>(hdecb, wout, bout,
                                                      pmax, psum, ptv, pti);
        dec_reduce<<<256, 256, 0, stream>>>(pmax, psum, ptv, pti,
                                            hdec, wout, bout, out, prev, t);
    }
}